// Round 1
// baseline (1496.130 us; speedup 1.0000x reference)
//
#include <hip/hip_runtime.h>
#include <hip/hip_bf16.h>

#define N_IT 49999
#define NI   50000
#define HD   128
#define MNB  16
#define BSZ  512
#define LSEQ 50
#define G3   384

__device__ __forceinline__ float wsum(float v) {
#pragma unroll
  for (int m = 32; m >= 1; m >>= 1) v += __shfl_xor(v, m, 64);
  return v;
}

__device__ __forceinline__ float sigmf(float x) {
  return 1.f / (1.f + __expf(-x));
}

// ---------------- normalize rows: o[r] = x[r]/max(||x[r]||,1e-12) ----------
__global__ void norm_kernel(const float* __restrict__ x, float* __restrict__ o, int n) {
  int w = threadIdx.x >> 6, l = threadIdx.x & 63;
  int r = blockIdx.x * 4 + w;
  if (r >= n) return;
  float a = x[(size_t)r * HD + l];
  float b = x[(size_t)r * HD + l + 64];
  float sq = wsum(a * a + b * b);
  float inv = 1.f / fmaxf(sqrtf(sq), 1e-12f);
  o[(size_t)r * HD + l] = a * inv;
  o[(size_t)r * HD + l + 64] = b * inv;
}

// ---------------- routing: one wave per node -------------------------------
__global__ void routing_kernel(const float* __restrict__ xn,
                               const int* __restrict__ adj,
                               float* __restrict__ out) {
  __shared__ float z[4][MNB][HD];
  int w = threadIdx.x >> 6, l = threadIdx.x & 63;
  int n = blockIdx.x * 4 + w;
  bool act = (n < N_IT);
  float xs0 = 0.f, xs1 = 0.f;
  if (act) {
#pragma unroll
    for (int m = 0; m < MNB; ++m) {
      int idx = adj[(size_t)n * MNB + m] - 1;
      z[w][m][l]      = xn[(size_t)idx * HD + l];
      z[w][m][l + 64] = xn[(size_t)idx * HD + l + 64];
    }
    xs0 = xn[(size_t)n * HD + l];
    xs1 = xn[(size_t)n * HD + l + 64];
  }
  __syncthreads();
  if (!act) return;

  float u0 = 0.f, u1 = 0.f;
#pragma unroll
  for (int m = 0; m < MNB; ++m) { u0 += z[w][m][l]; u1 += z[w][m][l + 64]; }
  u0 = u0 * (1.f / MNB) + xs0;
  u1 = u1 * (1.f / MNB) + xs1;

  for (int it = 0; it < 3; ++it) {
    float sq = wsum(u0 * u0 + u1 * u1);
    float nr = sqrtf(sq);
    float s = (sq / (sq + 1.f)) / fmaxf(nr, 1e-12f);
    u0 *= s; u1 *= s;
    float lg[MNB];
#pragma unroll
    for (int m = 0; m < MNB; ++m)
      lg[m] = wsum(z[w][m][l] * u0 + z[w][m][l + 64] * u1);
    float mx = lg[0];
#pragma unroll
    for (int m = 1; m < MNB; ++m) mx = fmaxf(mx, lg[m]);
    float se = 0.f;
#pragma unroll
    for (int m = 0; m < MNB; ++m) { lg[m] = __expf(lg[m] - mx); se += lg[m]; }
    float inv = 1.f / se;
    u0 = xs0; u1 = xs1;
#pragma unroll
    for (int m = 0; m < MNB; ++m) {
      float p = lg[m] * inv;
      u0 += z[w][m][l] * p;
      u1 += z[w][m][l + 64] * p;
    }
  }
  out[(size_t)n * HD + l] = u0;
  out[(size_t)n * HD + l + 64] = u1;
}

// ---------------- iv table: row0=0; rows 1..: LN1(x0 + o1 + o2) ------------
__global__ void iv_kernel(const float* __restrict__ item_emb,
                          const float* __restrict__ o1, const float* __restrict__ o2,
                          const float* __restrict__ g, const float* __restrict__ bb,
                          float* __restrict__ table) {
  int w = threadIdx.x >> 6, l = threadIdx.x & 63;
  int r = blockIdx.x * 4 + w;
  if (r >= NI) return;
  if (r == 0) { table[l] = 0.f; table[l + 64] = 0.f; return; }
  size_t pr = (size_t)(r - 1) * HD;
  float a = item_emb[(size_t)r * HD + l]      + o1[pr + l]      + o2[pr + l];
  float b = item_emb[(size_t)r * HD + l + 64] + o1[pr + l + 64] + o2[pr + l + 64];
  float mu = wsum(a + b) * (1.f / HD);
  float v  = wsum(a * a + b * b) * (1.f / HD) - mu * mu;
  float rs = rsqrtf(v + 1e-5f);
  table[(size_t)r * HD + l]      = (a - mu) * rs * g[l] + bb[l];
  table[(size_t)r * HD + l + 64] = (b - mu) * rs * g[l + 64] + bb[l + 64];
}

// ---------------- cls table: LN3(prob_emb @ W_cls.T) over all rows ---------
__global__ void cls_kernel(const float* __restrict__ prob, const float* __restrict__ Wc,
                           const float* __restrict__ g, const float* __restrict__ bb,
                           float* __restrict__ ct) {
  int w = threadIdx.x >> 6, l = threadIdx.x & 63;
  int r = blockIdx.x * 4 + w;
  if (r >= NI) return;
  float p[10];
#pragma unroll
  for (int k = 0; k < 10; ++k) p[k] = prob[(size_t)r * 10 + k];
  float a = 0.f, b = 0.f;
#pragma unroll
  for (int k = 0; k < 10; ++k) {
    a += p[k] * Wc[l * 10 + k];
    b += p[k] * Wc[(l + 64) * 10 + k];
  }
  float mu = wsum(a + b) * (1.f / HD);
  float v  = wsum(a * a + b * b) * (1.f / HD) - mu * mu;
  float rs = rsqrtf(v + 1e-5f);
  ct[(size_t)r * HD + l]      = (a - mu) * rs * g[l] + bb[l];
  ct[(size_t)r * HD + l + 64] = (b - mu) * rs * g[l + 64] + bb[l + 64];
}

// ---------------- gi precompute: gi[row][j] = dot(x_row, Wih[j]) + bih[j] --
// rows 0..25599 item path (gather from table), 25600..51199 cls path (from ct)
__global__ __launch_bounds__(384) void gi_kernel(
    const float* __restrict__ table, const float* __restrict__ ct,
    const int* __restrict__ sess, const float* __restrict__ Wih,
    const float* __restrict__ bih, float* __restrict__ gi) {
  __shared__ float xs[32][HD];
  __shared__ int sidx[32];
  int row0 = blockIdx.x * 32;
  int tid = threadIdx.x;
  if (tid < 32) {
    int rp = (row0 + tid) % 25600;
    sidx[tid] = sess[rp];
  }
  __syncthreads();
  const float* src = (row0 < 25600) ? table : ct;
  for (int i = tid; i < 32 * HD; i += 384) {
    int r = i >> 7, d = i & 127;
    xs[r][d] = src[(size_t)sidx[r] * HD + d];
  }
  __syncthreads();
  int j = tid;
  float bj = bih[j];
  const float4* W4 = reinterpret_cast<const float4*>(Wih + (size_t)j * HD);
  float acc[32];
#pragma unroll
  for (int r = 0; r < 32; ++r) acc[r] = 0.f;
  for (int kc = 0; kc < 32; ++kc) {
    float4 wv = W4[kc];
#pragma unroll
    for (int r = 0; r < 32; ++r) {
      float4 xv = reinterpret_cast<const float4*>(xs[r])[kc];
      acc[r] += wv.x * xv.x + wv.y * xv.y + wv.z * xv.z + wv.w * xv.w;
    }
  }
#pragma unroll
  for (int r = 0; r < 32; ++r)
    gi[(size_t)(row0 + r) * G3 + j] = acc[r] + bj;
}

// ---------------- GRU recurrence, both paths; snapshot h at t=len-1 --------
// grid 256: path = blk>>7, rows r0 = (blk&127)*4. 384 threads: thread j owns Whh[j] in regs.
__global__ __launch_bounds__(384, 1) void gru_kernel(
    const float* __restrict__ gi_all, const float* __restrict__ Whh,
    const float* __restrict__ bhh, const int* __restrict__ lengths,
    float* __restrict__ ht_raw) {
  __shared__ float h[4][HD];
  __shared__ float G[4][G3];
  __shared__ int lens[4];
  int tid = threadIdx.x;
  int p = blockIdx.x >> 7;
  int r0 = (blockIdx.x & 127) * 4;
  for (int i = tid; i < 4 * HD; i += 384) h[i >> 7][i & 127] = 0.f;
  if (tid < 4) lens[tid] = lengths[r0 + tid] - 1;
  float4 wreg[32];
  const float4* W4 = reinterpret_cast<const float4*>(Whh + (size_t)tid * HD);
#pragma unroll
  for (int kc = 0; kc < 32; ++kc) wreg[kc] = W4[kc];
  float bj = bhh[tid];
  const float* gi_base = gi_all + ((size_t)p * 25600 + (size_t)r0 * LSEQ) * G3;
  __syncthreads();
  for (int t = 0; t < LSEQ; ++t) {
    float a0 = 0.f, a1 = 0.f, a2 = 0.f, a3 = 0.f;
#pragma unroll
    for (int kc = 0; kc < 32; ++kc) {
      float4 wv = wreg[kc];
      float4 h0 = reinterpret_cast<const float4*>(h[0])[kc];
      float4 h1 = reinterpret_cast<const float4*>(h[1])[kc];
      float4 h2 = reinterpret_cast<const float4*>(h[2])[kc];
      float4 h3 = reinterpret_cast<const float4*>(h[3])[kc];
      a0 += wv.x * h0.x + wv.y * h0.y + wv.z * h0.z + wv.w * h0.w;
      a1 += wv.x * h1.x + wv.y * h1.y + wv.z * h1.z + wv.w * h1.w;
      a2 += wv.x * h2.x + wv.y * h2.y + wv.z * h2.z + wv.w * h2.w;
      a3 += wv.x * h3.x + wv.y * h3.y + wv.z * h3.z + wv.w * h3.w;
    }
    G[0][tid] = a0 + bj; G[1][tid] = a1 + bj; G[2][tid] = a2 + bj; G[3][tid] = a3 + bj;
    __syncthreads();
    for (int i = tid; i < 4 * HD; i += 384) {
      int r = i >> 7, d = i & 127;
      const float* grow = gi_base + ((size_t)r * LSEQ + t) * G3;
      float rg = sigmf(grow[d] + G[r][d]);
      float zg = sigmf(grow[HD + d] + G[r][HD + d]);
      float ng = tanhf(grow[2 * HD + d] + rg * G[r][2 * HD + d]);
      float hv = h[r][d];
      float hnew = (1.f - zg) * ng + zg * hv;
      h[r][d] = hnew;
      if (t == lens[r])
        ht_raw[((size_t)p * BSZ + r0 + r) * HD + d] = hnew;
    }
    __syncthreads();
  }
}

// ---------------- layernorm ht in place (rows 0..511: ln2, 512..1023: ln4) -
__global__ void ln_ht_kernel(float* __restrict__ ht,
                             const float* __restrict__ g2, const float* __restrict__ b2,
                             const float* __restrict__ g4, const float* __restrict__ b4) {
  int w = threadIdx.x >> 6, l = threadIdx.x & 63;
  int r = blockIdx.x * 4 + w;
  if (r >= 2 * BSZ) return;
  const float* g = (r < BSZ) ? g2 : g4;
  const float* bb = (r < BSZ) ? b2 : b4;
  float a = ht[(size_t)r * HD + l];
  float b = ht[(size_t)r * HD + l + 64];
  float mu = wsum(a + b) * (1.f / HD);
  float v  = wsum(a * a + b * b) * (1.f / HD) - mu * mu;
  float rs = rsqrtf(v + 1e-5f);
  ht[(size_t)r * HD + l]      = (a - mu) * rs * g[l] + bb[l];
  ht[(size_t)r * HD + l + 64] = (b - mu) * rs * g[l + 64] + bb[l + 64];
}

// ---------------- scores ---------------------------------------------------
// grid (391, 8), block 256. tile: 128 items x 64 rows.
__global__ void scores_kernel(const float* __restrict__ ht,
                              const float* __restrict__ table,
                              const float* __restrict__ ct,
                              const float* __restrict__ a1p, const float* __restrict__ a2p,
                              float* __restrict__ out) {
  __shared__ float hs[64][HD];
  __shared__ float cs[64][HD];
  int tid = threadIdx.x;
  int r0 = blockIdx.y * 64;
  int j0 = blockIdx.x * 128;
  for (int i = tid; i < 64 * HD; i += 256) {
    int r = i >> 7, d = i & 127;
    hs[r][d] = ht[(size_t)(r0 + r) * HD + d];
    cs[r][d] = ht[(size_t)(BSZ + r0 + r) * HD + d];
  }
  __syncthreads();
  float sa1 = sigmf(a1p[0]);
  float sa2 = sigmf(a2p[0]);
  int ig = tid & 31, rg = tid >> 5;
  int jb = j0 + ig * 4;
  int rb = rg * 8;
  float acc1[4][8], acc2[4][8];
#pragma unroll
  for (int c = 0; c < 4; ++c)
#pragma unroll
    for (int r = 0; r < 8; ++r) { acc1[c][r] = 0.f; acc2[c][r] = 0.f; }

  const float4* iv4[4];
  const float4* cv4[4];
#pragma unroll
  for (int c = 0; c < 4; ++c) {
    int j = jb + c;
    int jc = (j < N_IT) ? j : (N_IT - 1);
    iv4[c] = reinterpret_cast<const float4*>(table + (size_t)(jc + 1) * HD);
    cv4[c] = reinterpret_cast<const float4*>(ct + (size_t)(jc + 1) * HD);
  }
  for (int kc = 0; kc < 32; ++kc) {
    float4 av[4], bv[4];
#pragma unroll
    for (int c = 0; c < 4; ++c) { av[c] = iv4[c][kc]; bv[c] = cv4[c][kc]; }
#pragma unroll
    for (int r = 0; r < 8; ++r) {
      float4 h4 = reinterpret_cast<const float4*>(hs[rb + r])[kc];
      float4 c4 = reinterpret_cast<const float4*>(cs[rb + r])[kc];
#pragma unroll
      for (int c = 0; c < 4; ++c) {
        acc1[c][r] += av[c].x * h4.x + av[c].y * h4.y + av[c].z * h4.z + av[c].w * h4.w;
        acc2[c][r] += bv[c].x * c4.x + bv[c].y * c4.y + bv[c].z * c4.z + bv[c].w * c4.w;
      }
    }
  }
  const size_t S = (size_t)BSZ * N_IT;
#pragma unroll
  for (int c = 0; c < 4; ++c) {
    int j = jb + c;
    if (j < N_IT) {
#pragma unroll
      for (int r = 0; r < 8; ++r) {
        size_t o = (size_t)(r0 + rb + r) * N_IT + j;
        float s1 = acc1[c][r], s2 = acc2[c][r];
        out[o] = sa1 * s1 + sa2 * s2;
        out[S + o] = s1;
        out[2 * S + o] = s2;
      }
    }
  }
}

extern "C" void kernel_launch(void* const* d_in, const int* in_sizes, int n_in,
                              void* d_out, int out_size, void* d_ws, size_t ws_size,
                              hipStream_t stream) {
  const float* item_emb = (const float*)d_in[0];
  const float* prob_emb = (const float*)d_in[1];
  const float* W_cls    = (const float*)d_in[2];
  const float* a1       = (const float*)d_in[3];
  const float* a2       = (const float*)d_in[4];
  const float* Wih      = (const float*)d_in[5];
  const float* Whh      = (const float*)d_in[6];
  const float* bih      = (const float*)d_in[7];
  const float* bhh      = (const float*)d_in[8];
  const float* ln1_g = (const float*)d_in[9];
  const float* ln1_b = (const float*)d_in[10];
  const float* ln2_g = (const float*)d_in[11];
  const float* ln2_b = (const float*)d_in[12];
  const float* ln3_g = (const float*)d_in[13];
  const float* ln3_b = (const float*)d_in[14];
  const float* ln4_g = (const float*)d_in[15];
  const float* ln4_b = (const float*)d_in[16];
  const int* inp_sess = (const int*)d_in[19];
  const int* lengths  = (const int*)d_in[20];
  const int* adj      = (const int*)d_in[21];
  float* out = (float*)d_out;

  float* ws = (float*)d_ws;
  const size_t SZ_ROW = (size_t)N_IT * HD;
  float* xn  = ws;
  float* o1  = xn + SZ_ROW;
  float* o2  = o1 + SZ_ROW;
  float* tbl = o2 + SZ_ROW;
  float* ct  = tbl + (size_t)NI * HD;
  float* gi  = ct + (size_t)NI * HD;
  float* htb = gi + (size_t)2 * 25600 * G3;

  int nb4 = (N_IT + 3) / 4;   // 12500
  int nb4i = (NI + 3) / 4;    // 12500

  // routing hops
  norm_kernel<<<nb4, 256, 0, stream>>>(item_emb + HD, xn, N_IT);
  routing_kernel<<<nb4, 256, 0, stream>>>(xn, adj + MNB, o1);
  norm_kernel<<<nb4, 256, 0, stream>>>(o1, xn, N_IT);
  routing_kernel<<<nb4, 256, 0, stream>>>(xn, adj + MNB, o2);
  // item table (row0 = 0) and cls table
  iv_kernel<<<nb4i, 256, 0, stream>>>(item_emb, o1, o2, ln1_g, ln1_b, tbl);
  cls_kernel<<<nb4i, 256, 0, stream>>>(prob_emb, W_cls, ln3_g, ln3_b, ct);
  // gi precompute for both GRU paths
  gi_kernel<<<1600, 384, 0, stream>>>(tbl, ct, inp_sess, Wih, bih, gi);
  // GRU recurrence (both paths), snapshot at lengths-1
  gru_kernel<<<256, 384, 0, stream>>>(gi, Whh, bhh, lengths, htb);
  ln_ht_kernel<<<256, 256, 0, stream>>>(htb, ln2_g, ln2_b, ln4_g, ln4_b);
  // scores
  dim3 sg((N_IT + 127) / 128, 8);
  scores_kernel<<<sg, 256, 0, stream>>>(htb, tbl, ct, a1, a2, out);
}

// Round 2
// 894.154 us; speedup vs baseline: 1.6732x; 1.6732x over previous
//
#include <hip/hip_runtime.h>
#include <hip/hip_bf16.h>

#define N_IT 49999
#define NI   50000
#define HD   128
#define MNB  16
#define BSZ  512
#define LSEQ 50
#define G3   384

typedef __attribute__((ext_vector_type(8))) short short8;
typedef __attribute__((ext_vector_type(4))) float f32x4;

__device__ __forceinline__ float wsum(float v) {
#pragma unroll
  for (int m = 32; m >= 1; m >>= 1) v += __shfl_xor(v, m, 64);
  return v;
}

__device__ __forceinline__ float sigmf(float x) {
  return 1.f / (1.f + __expf(-x));
}

__device__ __forceinline__ unsigned short f2bf(float f) {
  unsigned u = __float_as_uint(f);
  u += 0x7FFF + ((u >> 16) & 1);
  return (unsigned short)(u >> 16);
}

// ---------------- normalize rows: o[r] = x[r]/max(||x[r]||,1e-12) ----------
__global__ void norm_kernel(const float* __restrict__ x, float* __restrict__ o, int n) {
  int w = threadIdx.x >> 6, l = threadIdx.x & 63;
  int r = blockIdx.x * 4 + w;
  if (r >= n) return;
  float a = x[(size_t)r * HD + l];
  float b = x[(size_t)r * HD + l + 64];
  float sq = wsum(a * a + b * b);
  float inv = 1.f / fmaxf(sqrtf(sq), 1e-12f);
  o[(size_t)r * HD + l] = a * inv;
  o[(size_t)r * HD + l + 64] = b * inv;
}

// ---------------- routing: one wave per node -------------------------------
__global__ void routing_kernel(const float* __restrict__ xn,
                               const int* __restrict__ adj,
                               float* __restrict__ out) {
  __shared__ float z[4][MNB][HD];
  int w = threadIdx.x >> 6, l = threadIdx.x & 63;
  int n = blockIdx.x * 4 + w;
  bool act = (n < N_IT);
  float xs0 = 0.f, xs1 = 0.f;
  if (act) {
#pragma unroll
    for (int m = 0; m < MNB; ++m) {
      int idx = adj[(size_t)n * MNB + m] - 1;
      z[w][m][l]      = xn[(size_t)idx * HD + l];
      z[w][m][l + 64] = xn[(size_t)idx * HD + l + 64];
    }
    xs0 = xn[(size_t)n * HD + l];
    xs1 = xn[(size_t)n * HD + l + 64];
  }
  __syncthreads();
  if (!act) return;

  float u0 = 0.f, u1 = 0.f;
#pragma unroll
  for (int m = 0; m < MNB; ++m) { u0 += z[w][m][l]; u1 += z[w][m][l + 64]; }
  u0 = u0 * (1.f / MNB) + xs0;
  u1 = u1 * (1.f / MNB) + xs1;

  for (int it = 0; it < 3; ++it) {
    float sq = wsum(u0 * u0 + u1 * u1);
    float nr = sqrtf(sq);
    float s = (sq / (sq + 1.f)) / fmaxf(nr, 1e-12f);
    u0 *= s; u1 *= s;
    float lg[MNB];
#pragma unroll
    for (int m = 0; m < MNB; ++m)
      lg[m] = wsum(z[w][m][l] * u0 + z[w][m][l + 64] * u1);
    float mx = lg[0];
#pragma unroll
    for (int m = 1; m < MNB; ++m) mx = fmaxf(mx, lg[m]);
    float se = 0.f;
#pragma unroll
    for (int m = 0; m < MNB; ++m) { lg[m] = __expf(lg[m] - mx); se += lg[m]; }
    float inv = 1.f / se;
    u0 = xs0; u1 = xs1;
#pragma unroll
    for (int m = 0; m < MNB; ++m) {
      float p = lg[m] * inv;
      u0 += z[w][m][l] * p;
      u1 += z[w][m][l + 64] * p;
    }
  }
  out[(size_t)n * HD + l] = u0;
  out[(size_t)n * HD + l + 64] = u1;
}

// ---------------- iv table: row0=0; rows 1..: LN1(x0 + o1 + o2) ------------
// also emits bf16 copy for the MFMA scores kernel
__global__ void iv_kernel(const float* __restrict__ item_emb,
                          const float* __restrict__ o1, const float* __restrict__ o2,
                          const float* __restrict__ g, const float* __restrict__ bb,
                          float* __restrict__ table, unsigned short* __restrict__ tbf) {
  int w = threadIdx.x >> 6, l = threadIdx.x & 63;
  int r = blockIdx.x * 4 + w;
  if (r >= NI) return;
  if (r == 0) {
    table[l] = 0.f; table[l + 64] = 0.f;
    tbf[l] = 0; tbf[l + 64] = 0;
    return;
  }
  size_t pr = (size_t)(r - 1) * HD;
  float a = item_emb[(size_t)r * HD + l]      + o1[pr + l]      + o2[pr + l];
  float b = item_emb[(size_t)r * HD + l + 64] + o1[pr + l + 64] + o2[pr + l + 64];
  float mu = wsum(a + b) * (1.f / HD);
  float v  = wsum(a * a + b * b) * (1.f / HD) - mu * mu;
  float rs = rsqrtf(v + 1e-5f);
  float va = (a - mu) * rs * g[l] + bb[l];
  float vb = (b - mu) * rs * g[l + 64] + bb[l + 64];
  table[(size_t)r * HD + l]      = va;
  table[(size_t)r * HD + l + 64] = vb;
  tbf[(size_t)r * HD + l]      = f2bf(va);
  tbf[(size_t)r * HD + l + 64] = f2bf(vb);
}

// ---------------- cls table: LN3(prob_emb @ W_cls.T) over all rows ---------
__global__ void cls_kernel(const float* __restrict__ prob, const float* __restrict__ Wc,
                           const float* __restrict__ g, const float* __restrict__ bb,
                           float* __restrict__ ct, unsigned short* __restrict__ cbf) {
  int w = threadIdx.x >> 6, l = threadIdx.x & 63;
  int r = blockIdx.x * 4 + w;
  if (r >= NI) return;
  float p[10];
#pragma unroll
  for (int k = 0; k < 10; ++k) p[k] = prob[(size_t)r * 10 + k];
  float a = 0.f, b = 0.f;
#pragma unroll
  for (int k = 0; k < 10; ++k) {
    a += p[k] * Wc[l * 10 + k];
    b += p[k] * Wc[(l + 64) * 10 + k];
  }
  float mu = wsum(a + b) * (1.f / HD);
  float v  = wsum(a * a + b * b) * (1.f / HD) - mu * mu;
  float rs = rsqrtf(v + 1e-5f);
  float va = (a - mu) * rs * g[l] + bb[l];
  float vb = (b - mu) * rs * g[l + 64] + bb[l + 64];
  ct[(size_t)r * HD + l]      = va;
  ct[(size_t)r * HD + l + 64] = vb;
  cbf[(size_t)r * HD + l]      = f2bf(va);
  cbf[(size_t)r * HD + l + 64] = f2bf(vb);
}

// ---------------- gi precompute: gi[row][j] = dot(x_row, Wih[j]) + bih[j] --
__global__ __launch_bounds__(384) void gi_kernel(
    const float* __restrict__ table, const float* __restrict__ ct,
    const int* __restrict__ sess, const float* __restrict__ Wih,
    const float* __restrict__ bih, float* __restrict__ gi) {
  __shared__ float xs[32][HD];
  __shared__ int sidx[32];
  int row0 = blockIdx.x * 32;
  int tid = threadIdx.x;
  if (tid < 32) {
    int rp = (row0 + tid) % 25600;
    sidx[tid] = sess[rp];
  }
  __syncthreads();
  const float* src = (row0 < 25600) ? table : ct;
  for (int i = tid; i < 32 * HD; i += 384) {
    int r = i >> 7, d = i & 127;
    xs[r][d] = src[(size_t)sidx[r] * HD + d];
  }
  __syncthreads();
  int j = tid;
  float bj = bih[j];
  const float4* W4 = reinterpret_cast<const float4*>(Wih + (size_t)j * HD);
  float acc[32];
#pragma unroll
  for (int r = 0; r < 32; ++r) acc[r] = 0.f;
  for (int kc = 0; kc < 32; ++kc) {
    float4 wv = W4[kc];
#pragma unroll
    for (int r = 0; r < 32; ++r) {
      float4 xv = reinterpret_cast<const float4*>(xs[r])[kc];
      acc[r] += wv.x * xv.x + wv.y * xv.y + wv.z * xv.z + wv.w * xv.w;
    }
  }
#pragma unroll
  for (int r = 0; r < 32; ++r)
    gi[(size_t)(row0 + r) * G3 + j] = acc[r] + bj;
}

// ---------------- GRU recurrence, both paths; snapshot h at t=len-1 --------
__global__ __launch_bounds__(384, 1) void gru_kernel(
    const float* __restrict__ gi_all, const float* __restrict__ Whh,
    const float* __restrict__ bhh, const int* __restrict__ lengths,
    float* __restrict__ ht_raw) {
  __shared__ float h[4][HD];
  __shared__ float G[4][G3];
  __shared__ int lens[4];
  int tid = threadIdx.x;
  int p = blockIdx.x >> 7;
  int r0 = (blockIdx.x & 127) * 4;
  for (int i = tid; i < 4 * HD; i += 384) h[i >> 7][i & 127] = 0.f;
  if (tid < 4) lens[tid] = lengths[r0 + tid] - 1;
  float4 wreg[32];
  const float4* W4 = reinterpret_cast<const float4*>(Whh + (size_t)tid * HD);
#pragma unroll
  for (int kc = 0; kc < 32; ++kc) wreg[kc] = W4[kc];
  float bj = bhh[tid];
  const float* gi_base = gi_all + ((size_t)p * 25600 + (size_t)r0 * LSEQ) * G3;
  __syncthreads();
  for (int t = 0; t < LSEQ; ++t) {
    float a0 = 0.f, a1 = 0.f, a2 = 0.f, a3 = 0.f;
#pragma unroll
    for (int kc = 0; kc < 32; ++kc) {
      float4 wv = wreg[kc];
      float4 h0 = reinterpret_cast<const float4*>(h[0])[kc];
      float4 h1 = reinterpret_cast<const float4*>(h[1])[kc];
      float4 h2 = reinterpret_cast<const float4*>(h[2])[kc];
      float4 h3 = reinterpret_cast<const float4*>(h[3])[kc];
      a0 += wv.x * h0.x + wv.y * h0.y + wv.z * h0.z + wv.w * h0.w;
      a1 += wv.x * h1.x + wv.y * h1.y + wv.z * h1.z + wv.w * h1.w;
      a2 += wv.x * h2.x + wv.y * h2.y + wv.z * h2.z + wv.w * h2.w;
      a3 += wv.x * h3.x + wv.y * h3.y + wv.z * h3.z + wv.w * h3.w;
    }
    G[0][tid] = a0 + bj; G[1][tid] = a1 + bj; G[2][tid] = a2 + bj; G[3][tid] = a3 + bj;
    __syncthreads();
    for (int i = tid; i < 4 * HD; i += 384) {
      int r = i >> 7, d = i & 127;
      const float* grow = gi_base + ((size_t)r * LSEQ + t) * G3;
      float rg = sigmf(grow[d] + G[r][d]);
      float zg = sigmf(grow[HD + d] + G[r][HD + d]);
      float ng = tanhf(grow[2 * HD + d] + rg * G[r][2 * HD + d]);
      float hv = h[r][d];
      float hnew = (1.f - zg) * ng + zg * hv;
      h[r][d] = hnew;
      if (t == lens[r])
        ht_raw[((size_t)p * BSZ + r0 + r) * HD + d] = hnew;
    }
    __syncthreads();
  }
}

// ---------------- layernorm ht in place + bf16 copy ------------------------
__global__ void ln_ht_kernel(float* __restrict__ ht,
                             const float* __restrict__ g2, const float* __restrict__ b2,
                             const float* __restrict__ g4, const float* __restrict__ b4,
                             unsigned short* __restrict__ hbf) {
  int w = threadIdx.x >> 6, l = threadIdx.x & 63;
  int r = blockIdx.x * 4 + w;
  if (r >= 2 * BSZ) return;
  const float* g = (r < BSZ) ? g2 : g4;
  const float* bb = (r < BSZ) ? b2 : b4;
  float a = ht[(size_t)r * HD + l];
  float b = ht[(size_t)r * HD + l + 64];
  float mu = wsum(a + b) * (1.f / HD);
  float v  = wsum(a * a + b * b) * (1.f / HD) - mu * mu;
  float rs = rsqrtf(v + 1e-5f);
  float va = (a - mu) * rs * g[l] + bb[l];
  float vb = (b - mu) * rs * g[l + 64] + bb[l + 64];
  ht[(size_t)r * HD + l]      = va;
  ht[(size_t)r * HD + l + 64] = vb;
  hbf[(size_t)r * HD + l]      = f2bf(va);
  hbf[(size_t)r * HD + l + 64] = f2bf(vb);
}

// ---------------- scores via MFMA bf16 -------------------------------------
// block = 256 (4 waves); each wave owns one 16-item j-tile, loops 32 row-tiles.
// A = ht (M=512 rows), B = table^T. mfma_f32_16x16x32_bf16:
//   A-frag: lane holds row (l&15), k = (l>>4)*8 + i   (bf16x8, 16B contiguous)
//   B-frag: lane holds col (l&15), same k
//   D: col = lane&15 (item j), row = (lane>>4)*4 + reg   [m89-verified]
__global__ __launch_bounds__(256) void scores_mfma_kernel(
    const unsigned short* __restrict__ hbf,   // 1024 x 128 bf16 (rows 512+ = cls)
    const unsigned short* __restrict__ tbf,   // 50000 x 128 bf16 (row j+1 = item j)
    const unsigned short* __restrict__ cbf,
    const float* __restrict__ a1p, const float* __restrict__ a2p,
    float* __restrict__ out) {
  int wave = threadIdx.x >> 6;
  int lane = threadIdx.x & 63;
  int jt = blockIdx.x * 4 + wave;
  if (jt >= 3125) return;
  int j0 = jt * 16;
  int jcol = j0 + (lane & 15);
  int jl = (jcol < N_IT) ? jcol : (N_IT - 1);
  int ko = (lane >> 4) * 8;

  short8 B1[4], B2[4];
#pragma unroll
  for (int kk = 0; kk < 4; ++kk) {
    B1[kk] = *(const short8*)(tbf + (size_t)(jl + 1) * HD + kk * 32 + ko);
    B2[kk] = *(const short8*)(cbf + (size_t)(jl + 1) * HD + kk * 32 + ko);
  }
  float sa1 = sigmf(a1p[0]);
  float sa2 = sigmf(a2p[0]);
  const size_t S = (size_t)BSZ * N_IT;
  int rrow = (lane >> 4) * 4;
  bool wr = (jcol < N_IT);

  for (int r0 = 0; r0 < BSZ; r0 += 16) {
    int ra = r0 + (lane & 15);
    f32x4 acc1 = {0.f, 0.f, 0.f, 0.f}, acc2 = {0.f, 0.f, 0.f, 0.f};
#pragma unroll
    for (int kk = 0; kk < 4; ++kk) {
      short8 A1 = *(const short8*)(hbf + (size_t)ra * HD + kk * 32 + ko);
      short8 A2 = *(const short8*)(hbf + (size_t)(BSZ + ra) * HD + kk * 32 + ko);
      acc1 = __builtin_amdgcn_mfma_f32_16x16x32_bf16(A1, B1[kk], acc1, 0, 0, 0);
      acc2 = __builtin_amdgcn_mfma_f32_16x16x32_bf16(A2, B2[kk], acc2, 0, 0, 0);
    }
    if (wr) {
#pragma unroll
      for (int gq = 0; gq < 4; ++gq) {
        size_t o = (size_t)(r0 + rrow + gq) * N_IT + jcol;
        float s1 = acc1[gq], s2 = acc2[gq];
        out[o]         = sa1 * s1 + sa2 * s2;
        out[S + o]     = s1;
        out[2 * S + o] = s2;
      }
    }
  }
}

extern "C" void kernel_launch(void* const* d_in, const int* in_sizes, int n_in,
                              void* d_out, int out_size, void* d_ws, size_t ws_size,
                              hipStream_t stream) {
  const float* item_emb = (const float*)d_in[0];
  const float* prob_emb = (const float*)d_in[1];
  const float* W_cls    = (const float*)d_in[2];
  const float* a1       = (const float*)d_in[3];
  const float* a2       = (const float*)d_in[4];
  const float* Wih      = (const float*)d_in[5];
  const float* Whh      = (const float*)d_in[6];
  const float* bih      = (const float*)d_in[7];
  const float* bhh      = (const float*)d_in[8];
  const float* ln1_g = (const float*)d_in[9];
  const float* ln1_b = (const float*)d_in[10];
  const float* ln2_g = (const float*)d_in[11];
  const float* ln2_b = (const float*)d_in[12];
  const float* ln3_g = (const float*)d_in[13];
  const float* ln3_b = (const float*)d_in[14];
  const float* ln4_g = (const float*)d_in[15];
  const float* ln4_b = (const float*)d_in[16];
  const int* inp_sess = (const int*)d_in[19];
  const int* lengths  = (const int*)d_in[20];
  const int* adj      = (const int*)d_in[21];
  float* out = (float*)d_out;

  float* ws = (float*)d_ws;
  const size_t SZ_ROW = (size_t)N_IT * HD;
  float* xn  = ws;
  float* o1  = xn + SZ_ROW;
  float* o2  = o1 + SZ_ROW;
  float* tbl = o2 + SZ_ROW;
  float* ct  = tbl + (size_t)NI * HD;
  float* gi  = ct + (size_t)NI * HD;
  float* htb = gi + (size_t)2 * 25600 * G3;

  // bf16 copies aliased into buffers that are dead by the time they're written:
  //  xn dead after 2nd routing; o2 dead after iv; o1 dead after iv.
  unsigned short* tbf = (unsigned short*)xn;   // 12.8 MB, written by iv (after routing)
  unsigned short* cbf = (unsigned short*)o2;   // 12.8 MB, written by cls (after iv)
  unsigned short* hbf = (unsigned short*)o1;   // 0.26 MB, written by ln_ht

  int nb4 = (N_IT + 3) / 4;
  int nb4i = (NI + 3) / 4;

  norm_kernel<<<nb4, 256, 0, stream>>>(item_emb + HD, xn, N_IT);
  routing_kernel<<<nb4, 256, 0, stream>>>(xn, adj + MNB, o1);
  norm_kernel<<<nb4, 256, 0, stream>>>(o1, xn, N_IT);
  routing_kernel<<<nb4, 256, 0, stream>>>(xn, adj + MNB, o2);
  iv_kernel<<<nb4i, 256, 0, stream>>>(item_emb, o1, o2, ln1_g, ln1_b, tbl, tbf);
  cls_kernel<<<nb4i, 256, 0, stream>>>(prob_emb, W_cls, ln3_g, ln3_b, ct, cbf);
  gi_kernel<<<1600, 384, 0, stream>>>(tbl, ct, inp_sess, Wih, bih, gi);
  gru_kernel<<<256, 384, 0, stream>>>(gi, Whh, bhh, lengths, htb);
  ln_ht_kernel<<<256, 256, 0, stream>>>(htb, ln2_g, ln2_b, ln4_g, ln4_b, hbf);
  scores_mfma_kernel<<<(3125 + 3) / 4, 256, 0, stream>>>(hbf, tbf, cbf, a1, a2, out);
}

// Round 4
// 771.396 us; speedup vs baseline: 1.9395x; 1.1591x over previous
//
#include <hip/hip_runtime.h>
#include <hip/hip_bf16.h>

#define N_IT 49999
#define NI   50000
#define HD   128
#define MNB  16
#define BSZ  512
#define LSEQ 50
#define G3   384

typedef __attribute__((ext_vector_type(8))) short short8;
typedef __attribute__((ext_vector_type(4))) float f32x4;

__device__ __forceinline__ float sigmf(float x) {
  return 1.f / (1.f + __expf(-x));
}

__device__ __forceinline__ unsigned short f2bf(float f) {
  unsigned u = __float_as_uint(f);
  u += 0x7FFF + ((u >> 16) & 1);
  return (unsigned short)(u >> 16);
}

// ---- wave64 sum: 4 DPP stages (VALU) + ds_swizzle(xor16) + ds_bpermute(xor32)
template <int CTRL>
__device__ __forceinline__ float dppadd(float v) {
  int s = __builtin_amdgcn_update_dpp(__float_as_int(v), __float_as_int(v),
                                      CTRL, 0xF, 0xF, false);
  return v + __int_as_float(s);
}

__device__ __forceinline__ float wsum(float v) {
  v = dppadd<0xB1>(v);    // pair swap   (i^1)
  v = dppadd<0x4E>(v);    // quad swap   (i^2)
  v = dppadd<0x141>(v);   // row_half_mirror (i^7)  -> 8-group sums
  v = dppadd<0x140>(v);   // row_mirror      (i^15) -> 16-row sums
  v += __int_as_float(__builtin_amdgcn_ds_swizzle(__float_as_int(v), 0x401F)); // i^16
  int lane = threadIdx.x & 63;
  v += __int_as_float(__builtin_amdgcn_ds_bpermute(((lane ^ 32) << 2),
                                                   __float_as_int(v)));       // i^32
  return v;
}

// ---------------- normalize rows; lane owns d={2l,2l+1}; fp32 + bf16x2 out --
__global__ void norm_kernel(const float* __restrict__ x, float* __restrict__ o,
                            unsigned* __restrict__ ob, int n) {
  int w = threadIdx.x >> 6, l = threadIdx.x & 63;
  int r = blockIdx.x * 4 + w;
  if (r >= n) return;
  float2 xv = *(const float2*)(x + (size_t)r * HD + 2 * l);
  float sq = wsum(xv.x * xv.x + xv.y * xv.y);
  float inv = 1.f / fmaxf(sqrtf(sq), 1e-12f);
  float a = xv.x * inv, b = xv.y * inv;
  *(float2*)(o + (size_t)r * HD + 2 * l) = make_float2(a, b);
  ob[(size_t)r * 64 + l] = (unsigned)f2bf(a) | ((unsigned)f2bf(b) << 16);
}

// ---------------- routing: one wave per node, z in registers ---------------
__global__ __launch_bounds__(256) void routing_kernel(
    const float* __restrict__ xn, const unsigned* __restrict__ xnb,
    const int* __restrict__ adj, float* __restrict__ out) {
  int w = threadIdx.x >> 6, l = threadIdx.x & 63;
  int n = blockIdx.x * 4 + w;
  if (n >= N_IT) return;

  float z0[MNB], z1[MNB];
#pragma unroll
  for (int m = 0; m < MNB; ++m) {
    int idx = adj[n * MNB + m] - 1;
    unsigned v = xnb[(size_t)idx * 64 + l];
    z0[m] = __int_as_float((v & 0xFFFFu) << 16);
    z1[m] = __int_as_float((v >> 16) << 16);
  }
  float2 xv = *(const float2*)(xn + (size_t)n * HD + 2 * l);
  float xs0 = xv.x, xs1 = xv.y;

  float u0 = 0.f, u1 = 0.f;
#pragma unroll
  for (int m = 0; m < MNB; ++m) { u0 += z0[m]; u1 += z1[m]; }
  u0 = u0 * (1.f / MNB) + xs0;
  u1 = u1 * (1.f / MNB) + xs1;

  for (int it = 0; it < 3; ++it) {
    float sq = wsum(u0 * u0 + u1 * u1);
    float s = (sq / (sq + 1.f)) / fmaxf(sqrtf(sq), 1e-12f);
    u0 *= s; u1 *= s;
    float lg[MNB];
#pragma unroll
    for (int m = 0; m < MNB; ++m)
      lg[m] = wsum(z0[m] * u0 + z1[m] * u1);
    // |lg| <= ||u|| < 1 -> softmax without max-subtraction is safe
    float se = 0.f;
#pragma unroll
    for (int m = 0; m < MNB; ++m) { lg[m] = __expf(lg[m]); se += lg[m]; }
    float inv = 1.f / se;
    u0 = xs0; u1 = xs1;
#pragma unroll
    for (int m = 0; m < MNB; ++m) {
      float p = lg[m] * inv;
      u0 += z0[m] * p;
      u1 += z1[m] * p;
    }
  }
  *(float2*)(out + (size_t)n * HD + 2 * l) = make_float2(u0, u1);
}

// ---------------- iv table: row0=0; rows 1..: LN1(x0 + o1 + o2) ------------
__global__ void iv_kernel(const float* __restrict__ item_emb,
                          const float* __restrict__ o1, const float* __restrict__ o2,
                          const float* __restrict__ g, const float* __restrict__ bb,
                          float* __restrict__ table, unsigned short* __restrict__ tbf) {
  int w = threadIdx.x >> 6, l = threadIdx.x & 63;
  int r = blockIdx.x * 4 + w;
  if (r >= NI) return;
  if (r == 0) {
    table[l] = 0.f; table[l + 64] = 0.f;
    tbf[l] = 0; tbf[l + 64] = 0;
    return;
  }
  size_t pr = (size_t)(r - 1) * HD;
  float a = item_emb[(size_t)r * HD + l]      + o1[pr + l]      + o2[pr + l];
  float b = item_emb[(size_t)r * HD + l + 64] + o1[pr + l + 64] + o2[pr + l + 64];
  float mu = wsum(a + b) * (1.f / HD);
  float v  = wsum(a * a + b * b) * (1.f / HD) - mu * mu;
  float rs = rsqrtf(v + 1e-5f);
  float va = (a - mu) * rs * g[l] + bb[l];
  float vb = (b - mu) * rs * g[l + 64] + bb[l + 64];
  table[(size_t)r * HD + l]      = va;
  table[(size_t)r * HD + l + 64] = vb;
  tbf[(size_t)r * HD + l]      = f2bf(va);
  tbf[(size_t)r * HD + l + 64] = f2bf(vb);
}

// ---------------- cls table: LN3(prob_emb @ W_cls.T) over all rows ---------
__global__ void cls_kernel(const float* __restrict__ prob, const float* __restrict__ Wc,
                           const float* __restrict__ g, const float* __restrict__ bb,
                           float* __restrict__ ct, unsigned short* __restrict__ cbf) {
  int w = threadIdx.x >> 6, l = threadIdx.x & 63;
  int r = blockIdx.x * 4 + w;
  if (r >= NI) return;
  float p[10];
#pragma unroll
  for (int k = 0; k < 10; ++k) p[k] = prob[(size_t)r * 10 + k];
  float a = 0.f, b = 0.f;
#pragma unroll
  for (int k = 0; k < 10; ++k) {
    a += p[k] * Wc[l * 10 + k];
    b += p[k] * Wc[(l + 64) * 10 + k];
  }
  float mu = wsum(a + b) * (1.f / HD);
  float v  = wsum(a * a + b * b) * (1.f / HD) - mu * mu;
  float rs = rsqrtf(v + 1e-5f);
  float va = (a - mu) * rs * g[l] + bb[l];
  float vb = (b - mu) * rs * g[l + 64] + bb[l + 64];
  ct[(size_t)r * HD + l]      = va;
  ct[(size_t)r * HD + l + 64] = vb;
  cbf[(size_t)r * HD + l]      = f2bf(va);
  cbf[(size_t)r * HD + l + 64] = f2bf(vb);
}

// ---------------- gi precompute: gi[row][j] = dot(x_row, Wih[j]) + bih[j] --
__global__ __launch_bounds__(384) void gi_kernel(
    const float* __restrict__ table, const float* __restrict__ ct,
    const int* __restrict__ sess, const float* __restrict__ Wih,
    const float* __restrict__ bih, float* __restrict__ gi) {
  __shared__ float xs[32][HD];
  __shared__ int sidx[32];
  int row0 = blockIdx.x * 32;
  int tid = threadIdx.x;
  if (tid < 32) {
    int rp = (row0 + tid) % 25600;
    sidx[tid] = sess[rp];
  }
  __syncthreads();
  const float* src = (row0 < 25600) ? table : ct;
  for (int i = tid; i < 32 * HD; i += 384) {
    int r = i >> 7, d = i & 127;
    xs[r][d] = src[(size_t)sidx[r] * HD + d];
  }
  __syncthreads();
  int j = tid;
  float bj = bih[j];
  const float4* W4 = reinterpret_cast<const float4*>(Wih + (size_t)j * HD);
  float acc[32];
#pragma unroll
  for (int r = 0; r < 32; ++r) acc[r] = 0.f;
  for (int kc = 0; kc < 32; ++kc) {
    float4 wv = W4[kc];
#pragma unroll
    for (int r = 0; r < 32; ++r) {
      float4 xv = reinterpret_cast<const float4*>(xs[r])[kc];
      acc[r] += wv.x * xv.x + wv.y * xv.y + wv.z * xv.z + wv.w * xv.w;
    }
  }
#pragma unroll
  for (int r = 0; r < 32; ++r)
    gi[(size_t)(row0 + r) * G3 + j] = acc[r] + bj;
}

// ---------------- GRU recurrence, both paths; snapshot h at t=len-1 --------
__global__ __launch_bounds__(384, 1) void gru_kernel(
    const float* __restrict__ gi_all, const float* __restrict__ Whh,
    const float* __restrict__ bhh, const int* __restrict__ lengths,
    float* __restrict__ ht_raw) {
  __shared__ float h[4][HD];
  __shared__ float G[4][G3];
  __shared__ int lens[4];
  int tid = threadIdx.x;
  int p = blockIdx.x >> 7;
  int r0 = (blockIdx.x & 127) * 4;
  for (int i = tid; i < 4 * HD; i += 384) h[i >> 7][i & 127] = 0.f;
  if (tid < 4) lens[tid] = lengths[r0 + tid] - 1;
  float4 wreg[32];
  const float4* W4 = reinterpret_cast<const float4*>(Whh + (size_t)tid * HD);
#pragma unroll
  for (int kc = 0; kc < 32; ++kc) wreg[kc] = W4[kc];
  float bj = bhh[tid];
  const float* gi_base = gi_all + ((size_t)p * 25600 + (size_t)r0 * LSEQ) * G3;
  __syncthreads();
  for (int t = 0; t < LSEQ; ++t) {
    float a0 = 0.f, a1 = 0.f, a2 = 0.f, a3 = 0.f;
#pragma unroll
    for (int kc = 0; kc < 32; ++kc) {
      float4 wv = wreg[kc];
      float4 h0 = reinterpret_cast<const float4*>(h[0])[kc];
      float4 h1 = reinterpret_cast<const float4*>(h[1])[kc];
      float4 h2 = reinterpret_cast<const float4*>(h[2])[kc];
      float4 h3 = reinterpret_cast<const float4*>(h[3])[kc];
      a0 += wv.x * h0.x + wv.y * h0.y + wv.z * h0.z + wv.w * h0.w;
      a1 += wv.x * h1.x + wv.y * h1.y + wv.z * h1.z + wv.w * h1.w;
      a2 += wv.x * h2.x + wv.y * h2.y + wv.z * h2.z + wv.w * h2.w;
      a3 += wv.x * h3.x + wv.y * h3.y + wv.z * h3.z + wv.w * h3.w;
    }
    G[0][tid] = a0 + bj; G[1][tid] = a1 + bj; G[2][tid] = a2 + bj; G[3][tid] = a3 + bj;
    __syncthreads();
    for (int i = tid; i < 4 * HD; i += 384) {
      int r = i >> 7, d = i & 127;
      const float* grow = gi_base + ((size_t)r * LSEQ + t) * G3;
      float rg = sigmf(grow[d] + G[r][d]);
      float zg = sigmf(grow[HD + d] + G[r][HD + d]);
      float ng = tanhf(grow[2 * HD + d] + rg * G[r][2 * HD + d]);
      float hv = h[r][d];
      float hnew = (1.f - zg) * ng + zg * hv;
      h[r][d] = hnew;
      if (t == lens[r])
        ht_raw[((size_t)p * BSZ + r0 + r) * HD + d] = hnew;
    }
    __syncthreads();
  }
}

// ---------------- layernorm ht in place + bf16 copy ------------------------
__global__ void ln_ht_kernel(float* __restrict__ ht,
                             const float* __restrict__ g2, const float* __restrict__ b2,
                             const float* __restrict__ g4, const float* __restrict__ b4,
                             unsigned short* __restrict__ hbf) {
  int w = threadIdx.x >> 6, l = threadIdx.x & 63;
  int r = blockIdx.x * 4 + w;
  if (r >= 2 * BSZ) return;
  const float* g = (r < BSZ) ? g2 : g4;
  const float* bb = (r < BSZ) ? b2 : b4;
  float a = ht[(size_t)r * HD + l];
  float b = ht[(size_t)r * HD + l + 64];
  float mu = wsum(a + b) * (1.f / HD);
  float v  = wsum(a * a + b * b) * (1.f / HD) - mu * mu;
  float rs = rsqrtf(v + 1e-5f);
  float va = (a - mu) * rs * g[l] + bb[l];
  float vb = (b - mu) * rs * g[l + 64] + bb[l + 64];
  ht[(size_t)r * HD + l]      = va;
  ht[(size_t)r * HD + l + 64] = vb;
  hbf[(size_t)r * HD + l]      = f2bf(va);
  hbf[(size_t)r * HD + l + 64] = f2bf(vb);
}

// ---------------- scores via MFMA bf16 -------------------------------------
__global__ __launch_bounds__(256) void scores_mfma_kernel(
    const unsigned short* __restrict__ hbf,
    const unsigned short* __restrict__ tbf,
    const unsigned short* __restrict__ cbf,
    const float* __restrict__ a1p, const float* __restrict__ a2p,
    float* __restrict__ out) {
  int wave = threadIdx.x >> 6;
  int lane = threadIdx.x & 63;
  int jt = blockIdx.x * 4 + wave;
  if (jt >= 3125) return;
  int j0 = jt * 16;
  int jcol = j0 + (lane & 15);
  int jl = (jcol < N_IT) ? jcol : (N_IT - 1);
  int ko = (lane >> 4) * 8;

  short8 B1[4], B2[4];
#pragma unroll
  for (int kk = 0; kk < 4; ++kk) {
    B1[kk] = *(const short8*)(tbf + (size_t)(jl + 1) * HD + kk * 32 + ko);
    B2[kk] = *(const short8*)(cbf + (size_t)(jl + 1) * HD + kk * 32 + ko);
  }
  float sa1 = sigmf(a1p[0]);
  float sa2 = sigmf(a2p[0]);
  const size_t S = (size_t)BSZ * N_IT;
  int rrow = (lane >> 4) * 4;
  bool wr = (jcol < N_IT);

  for (int r0 = 0; r0 < BSZ; r0 += 16) {
    int ra = r0 + (lane & 15);
    f32x4 acc1 = {0.f, 0.f, 0.f, 0.f}, acc2 = {0.f, 0.f, 0.f, 0.f};
#pragma unroll
    for (int kk = 0; kk < 4; ++kk) {
      short8 A1 = *(const short8*)(hbf + (size_t)ra * HD + kk * 32 + ko);
      short8 A2 = *(const short8*)(hbf + (size_t)(BSZ + ra) * HD + kk * 32 + ko);
      acc1 = __builtin_amdgcn_mfma_f32_16x16x32_bf16(A1, B1[kk], acc1, 0, 0, 0);
      acc2 = __builtin_amdgcn_mfma_f32_16x16x32_bf16(A2, B2[kk], acc2, 0, 0, 0);
    }
    if (wr) {
#pragma unroll
      for (int gq = 0; gq < 4; ++gq) {
        size_t o = (size_t)(r0 + rrow + gq) * N_IT + jcol;
        float s1 = acc1[gq], s2 = acc2[gq];
        out[o]         = sa1 * s1 + sa2 * s2;
        out[S + o]     = s1;
        out[2 * S + o] = s2;
      }
    }
  }
}

extern "C" void kernel_launch(void* const* d_in, const int* in_sizes, int n_in,
                              void* d_out, int out_size, void* d_ws, size_t ws_size,
                              hipStream_t stream) {
  const float* item_emb = (const float*)d_in[0];
  const float* prob_emb = (const float*)d_in[1];
  const float* W_cls    = (const float*)d_in[2];
  const float* a1       = (const float*)d_in[3];
  const float* a2       = (const float*)d_in[4];
  const float* Wih      = (const float*)d_in[5];
  const float* Whh      = (const float*)d_in[6];
  const float* bih      = (const float*)d_in[7];
  const float* bhh      = (const float*)d_in[8];
  const float* ln1_g = (const float*)d_in[9];
  const float* ln1_b = (const float*)d_in[10];
  const float* ln2_g = (const float*)d_in[11];
  const float* ln2_b = (const float*)d_in[12];
  const float* ln3_g = (const float*)d_in[13];
  const float* ln3_b = (const float*)d_in[14];
  const float* ln4_g = (const float*)d_in[15];
  const float* ln4_b = (const float*)d_in[16];
  const int* inp_sess = (const int*)d_in[19];
  const int* lengths  = (const int*)d_in[20];
  const int* adj      = (const int*)d_in[21];
  float* out = (float*)d_out;

  float* ws = (float*)d_ws;
  const size_t SZ_ROW = (size_t)N_IT * HD;
  float* xn  = ws;
  float* o1  = xn + SZ_ROW;
  float* o2  = o1 + SZ_ROW;
  float* tbl = o2 + SZ_ROW;
  float* ct  = tbl + (size_t)NI * HD;
  float* gi  = ct + (size_t)NI * HD;
  float* htb = gi + (size_t)2 * 25600 * G3;

  // aliases into dead regions:
  unsigned* xnb = (unsigned*)gi;               // bf16 normalized rows (dead before gi_kernel)
  unsigned short* tbf = (unsigned short*)xn;   // written by iv (xn dead after hop2)
  unsigned short* cbf = (unsigned short*)o2;   // written by cls (o2 dead after iv)
  unsigned short* hbf = (unsigned short*)o1;   // written by ln_ht (o1 dead after iv)

  int nb4 = (N_IT + 3) / 4;
  int nb4i = (NI + 3) / 4;

  norm_kernel<<<nb4, 256, 0, stream>>>(item_emb + HD, xn, xnb, N_IT);
  routing_kernel<<<nb4, 256, 0, stream>>>(xn, xnb, adj + MNB, o1);
  norm_kernel<<<nb4, 256, 0, stream>>>(o1, xn, xnb, N_IT);
  routing_kernel<<<nb4, 256, 0, stream>>>(xn, xnb, adj + MNB, o2);
  iv_kernel<<<nb4i, 256, 0, stream>>>(item_emb, o1, o2, ln1_g, ln1_b, tbl, tbf);
  cls_kernel<<<nb4i, 256, 0, stream>>>(prob_emb, W_cls, ln3_g, ln3_b, ct, cbf);
  gi_kernel<<<1600, 384, 0, stream>>>(tbl, ct, inp_sess, Wih, bih, gi);
  gru_kernel<<<256, 384, 0, stream>>>(gi, Whh, bhh, lengths, htb);
  ln_ht_kernel<<<256, 256, 0, stream>>>(htb, ln2_g, ln2_b, ln4_g, ln4_b, hbf);
  scores_mfma_kernel<<<(3125 + 3) / 4, 256, 0, stream>>>(hbf, tbf, cbf, a1, a2, out);
}

// Round 5
// 664.495 us; speedup vs baseline: 2.2515x; 1.1609x over previous
//
#include <hip/hip_runtime.h>
#include <hip/hip_bf16.h>

#define N_IT 49999
#define NI   50000
#define HD   128
#define MNB  16
#define BSZ  512
#define LSEQ 50
#define G3   384

typedef __attribute__((ext_vector_type(8))) short short8;
typedef __attribute__((ext_vector_type(4))) float f32x4;

__device__ __forceinline__ float sigmf(float x) {
  return 1.f / (1.f + __expf(-x));
}
__device__ __forceinline__ float fast_sigm(float x) {
  return __fdividef(1.f, 1.f + __expf(-x));
}
__device__ __forceinline__ float fast_tanh(float x) {
  float e = __expf(-2.f * x);
  return (1.f - e) * __fdividef(1.f, 1.f + e);
}

__device__ __forceinline__ unsigned short f2bf(float f) {
  unsigned u = __float_as_uint(f);
  u += 0x7FFF + ((u >> 16) & 1);
  return (unsigned short)(u >> 16);
}

// ---- wave64 sum: 4 DPP stages (VALU) + ds_swizzle(xor16) + ds_bpermute(xor32)
template <int CTRL>
__device__ __forceinline__ float dppadd(float v) {
  int s = __builtin_amdgcn_update_dpp(__float_as_int(v), __float_as_int(v),
                                      CTRL, 0xF, 0xF, false);
  return v + __int_as_float(s);
}

__device__ __forceinline__ float wsum(float v) {
  v = dppadd<0xB1>(v);    // pair swap   (i^1)
  v = dppadd<0x4E>(v);    // quad swap   (i^2)
  v = dppadd<0x141>(v);   // row_half_mirror (i^7)
  v = dppadd<0x140>(v);   // row_mirror      (i^15)
  v += __int_as_float(__builtin_amdgcn_ds_swizzle(__float_as_int(v), 0x401F)); // i^16
  int lane = threadIdx.x & 63;
  v += __int_as_float(__builtin_amdgcn_ds_bpermute(((lane ^ 32) << 2),
                                                   __float_as_int(v)));       // i^32
  return v;
}

// ---------------- normalize rows; lane owns d={2l,2l+1}; fp32 + bf16x2 out --
__global__ void norm_kernel(const float* __restrict__ x, float* __restrict__ o,
                            unsigned* __restrict__ ob, int n) {
  int w = threadIdx.x >> 6, l = threadIdx.x & 63;
  int r = blockIdx.x * 4 + w;
  if (r >= n) return;
  float2 xv = *(const float2*)(x + (size_t)r * HD + 2 * l);
  float sq = wsum(xv.x * xv.x + xv.y * xv.y);
  float inv = 1.f / fmaxf(sqrtf(sq), 1e-12f);
  float a = xv.x * inv, b = xv.y * inv;
  *(float2*)(o + (size_t)r * HD + 2 * l) = make_float2(a, b);
  ob[(size_t)r * 64 + l] = (unsigned)f2bf(a) | ((unsigned)f2bf(b) << 16);
}

// ---------------- routing: one wave per node, z in registers ---------------
__global__ __launch_bounds__(256) void routing_kernel(
    const float* __restrict__ xn, const unsigned* __restrict__ xnb,
    const int* __restrict__ adj, float* __restrict__ out) {
  int w = threadIdx.x >> 6, l = threadIdx.x & 63;
  int n = blockIdx.x * 4 + w;
  if (n >= N_IT) return;

  float z0[MNB], z1[MNB];
#pragma unroll
  for (int m = 0; m < MNB; ++m) {
    int idx = adj[n * MNB + m] - 1;
    unsigned v = xnb[(size_t)idx * 64 + l];
    z0[m] = __int_as_float((v & 0xFFFFu) << 16);
    z1[m] = __int_as_float((v >> 16) << 16);
  }
  float2 xv = *(const float2*)(xn + (size_t)n * HD + 2 * l);
  float xs0 = xv.x, xs1 = xv.y;

  float u0 = 0.f, u1 = 0.f;
#pragma unroll
  for (int m = 0; m < MNB; ++m) { u0 += z0[m]; u1 += z1[m]; }
  u0 = u0 * (1.f / MNB) + xs0;
  u1 = u1 * (1.f / MNB) + xs1;

  for (int it = 0; it < 3; ++it) {
    float sq = wsum(u0 * u0 + u1 * u1);
    float s = (sq / (sq + 1.f)) / fmaxf(sqrtf(sq), 1e-12f);
    u0 *= s; u1 *= s;
    float lg[MNB];
#pragma unroll
    for (int m = 0; m < MNB; ++m)
      lg[m] = wsum(z0[m] * u0 + z1[m] * u1);
    float se = 0.f;
#pragma unroll
    for (int m = 0; m < MNB; ++m) { lg[m] = __expf(lg[m]); se += lg[m]; }
    float inv = 1.f / se;
    u0 = xs0; u1 = xs1;
#pragma unroll
    for (int m = 0; m < MNB; ++m) {
      float p = lg[m] * inv;
      u0 += z0[m] * p;
      u1 += z1[m] * p;
    }
  }
  *(float2*)(out + (size_t)n * HD + 2 * l) = make_float2(u0, u1);
}

// ---------------- iv table: row0=0; rows 1..: LN1(x0 + o1 + o2) ------------
__global__ void iv_kernel(const float* __restrict__ item_emb,
                          const float* __restrict__ o1, const float* __restrict__ o2,
                          const float* __restrict__ g, const float* __restrict__ bb,
                          float* __restrict__ table, unsigned short* __restrict__ tbf) {
  int w = threadIdx.x >> 6, l = threadIdx.x & 63;
  int r = blockIdx.x * 4 + w;
  if (r >= NI) return;
  if (r == 0) {
    table[l] = 0.f; table[l + 64] = 0.f;
    tbf[l] = 0; tbf[l + 64] = 0;
    return;
  }
  size_t pr = (size_t)(r - 1) * HD;
  float a = item_emb[(size_t)r * HD + l]      + o1[pr + l]      + o2[pr + l];
  float b = item_emb[(size_t)r * HD + l + 64] + o1[pr + l + 64] + o2[pr + l + 64];
  float mu = wsum(a + b) * (1.f / HD);
  float v  = wsum(a * a + b * b) * (1.f / HD) - mu * mu;
  float rs = rsqrtf(v + 1e-5f);
  float va = (a - mu) * rs * g[l] + bb[l];
  float vb = (b - mu) * rs * g[l + 64] + bb[l + 64];
  table[(size_t)r * HD + l]      = va;
  table[(size_t)r * HD + l + 64] = vb;
  tbf[(size_t)r * HD + l]      = f2bf(va);
  tbf[(size_t)r * HD + l + 64] = f2bf(vb);
}

// ---------------- cls table: LN3(prob_emb @ W_cls.T) over all rows ---------
__global__ void cls_kernel(const float* __restrict__ prob, const float* __restrict__ Wc,
                           const float* __restrict__ g, const float* __restrict__ bb,
                           float* __restrict__ ct, unsigned short* __restrict__ cbf) {
  int w = threadIdx.x >> 6, l = threadIdx.x & 63;
  int r = blockIdx.x * 4 + w;
  if (r >= NI) return;
  float p[10];
#pragma unroll
  for (int k = 0; k < 10; ++k) p[k] = prob[(size_t)r * 10 + k];
  float a = 0.f, b = 0.f;
#pragma unroll
  for (int k = 0; k < 10; ++k) {
    a += p[k] * Wc[l * 10 + k];
    b += p[k] * Wc[(l + 64) * 10 + k];
  }
  float mu = wsum(a + b) * (1.f / HD);
  float v  = wsum(a * a + b * b) * (1.f / HD) - mu * mu;
  float rs = rsqrtf(v + 1e-5f);
  float va = (a - mu) * rs * g[l] + bb[l];
  float vb = (b - mu) * rs * g[l + 64] + bb[l + 64];
  ct[(size_t)r * HD + l]      = va;
  ct[(size_t)r * HD + l + 64] = vb;
  cbf[(size_t)r * HD + l]      = f2bf(va);
  cbf[(size_t)r * HD + l + 64] = f2bf(vb);
}

// ---------------- gi precompute: gi[row][j] = dot(x_row, Wih[j]) + bih[j] --
__global__ __launch_bounds__(384) void gi_kernel(
    const float* __restrict__ table, const float* __restrict__ ct,
    const int* __restrict__ sess, const float* __restrict__ Wih,
    const float* __restrict__ bih, float* __restrict__ gi) {
  __shared__ float xs[32][HD];
  __shared__ int sidx[32];
  int row0 = blockIdx.x * 32;
  int tid = threadIdx.x;
  if (tid < 32) {
    int rp = (row0 + tid) % 25600;
    sidx[tid] = sess[rp];
  }
  __syncthreads();
  const float* src = (row0 < 25600) ? table : ct;
  for (int i = tid; i < 32 * HD; i += 384) {
    int r = i >> 7, d = i & 127;
    xs[r][d] = src[(size_t)sidx[r] * HD + d];
  }
  __syncthreads();
  int j = tid;
  float bj = bih[j];
  const float4* W4 = reinterpret_cast<const float4*>(Wih + (size_t)j * HD);
  float acc[32];
#pragma unroll
  for (int r = 0; r < 32; ++r) acc[r] = 0.f;
  for (int kc = 0; kc < 32; ++kc) {
    float4 wv = W4[kc];
#pragma unroll
    for (int r = 0; r < 32; ++r) {
      float4 xv = reinterpret_cast<const float4*>(xs[r])[kc];
      acc[r] += wv.x * xv.x + wv.y * xv.y + wv.z * xv.z + wv.w * xv.w;
    }
  }
#pragma unroll
  for (int r = 0; r < 32; ++r)
    gi[(size_t)(row0 + r) * G3 + j] = acc[r] + bj;
}

// ---------------- GRU recurrence via MFMA ----------------------------------
// 64 blocks: p = blk>>5, row-tile rt = blk&31 (16 rows). 512 threads = 8 waves.
// Wave w owns gate-tiles {16w, 128+16w, 256+16w}: its D-frags hold the matching
// r/z/n gates for its own (row,d) items -> elementwise entirely in registers.
// h: bf16 in double-buffered swizzled LDS (byte ^= (row&7)<<4); fp32 h in regs.
__global__ __launch_bounds__(512) void gru_mfma_kernel(
    const float* __restrict__ gi_all, const float* __restrict__ Whh,
    const float* __restrict__ bhh, const int* __restrict__ lengths,
    float* __restrict__ ht_raw) {
  __shared__ unsigned short hlds[2][16 * HD];  // 8 KB
  int tid = threadIdx.x;
  int lane = tid & 63;
  int w = tid >> 6;
  int p = blockIdx.x >> 5;
  int r0 = (blockIdx.x & 31) * 16;
  int cN = lane & 15;       // gate-within-tile == d-within-16, and A-row for reads
  int quad = lane >> 4;
  int d = w * 16 + cN;      // 0..127

  // zero both h buffers
  {
    int* hz = (int*)hlds;
    for (int i = tid; i < 2 * 16 * HD / 2; i += 512) hz[i] = 0;
  }

  // B-fragments (Whh rows d, 128+d, 256+d) in bf16 registers
  short8 Br[4], Bz[4], Bn[4];
#pragma unroll
  for (int kk = 0; kk < 4; ++kk) {
    int kbase = quad * 8 + kk * 32;
    const float* wr_ = Whh + (size_t)d * HD + kbase;
    const float* wz_ = Whh + (size_t)(128 + d) * HD + kbase;
    const float* wn_ = Whh + (size_t)(256 + d) * HD + kbase;
    float4 r0v = *(const float4*)wr_, r1v = *(const float4*)(wr_ + 4);
    float4 z0v = *(const float4*)wz_, z1v = *(const float4*)(wz_ + 4);
    float4 n0v = *(const float4*)wn_, n1v = *(const float4*)(wn_ + 4);
    short8 br, bz, bn;
    br[0]=(short)f2bf(r0v.x); br[1]=(short)f2bf(r0v.y); br[2]=(short)f2bf(r0v.z); br[3]=(short)f2bf(r0v.w);
    br[4]=(short)f2bf(r1v.x); br[5]=(short)f2bf(r1v.y); br[6]=(short)f2bf(r1v.z); br[7]=(short)f2bf(r1v.w);
    bz[0]=(short)f2bf(z0v.x); bz[1]=(short)f2bf(z0v.y); bz[2]=(short)f2bf(z0v.z); bz[3]=(short)f2bf(z0v.w);
    bz[4]=(short)f2bf(z1v.x); bz[5]=(short)f2bf(z1v.y); bz[6]=(short)f2bf(z1v.z); bz[7]=(short)f2bf(z1v.w);
    bn[0]=(short)f2bf(n0v.x); bn[1]=(short)f2bf(n0v.y); bn[2]=(short)f2bf(n0v.z); bn[3]=(short)f2bf(n0v.w);
    bn[4]=(short)f2bf(n1v.x); bn[5]=(short)f2bf(n1v.y); bn[6]=(short)f2bf(n1v.z); bn[7]=(short)f2bf(n1v.w);
    Br[kk] = br; Bz[kk] = bz; Bn[kk] = bn;
  }
  float bhr = bhh[d], bhz = bhh[128 + d], bhn = bhh[256 + d];

  // per-lane rows (lr = quad*4+gq): lengths, h fp32, gi pointers
  int lens4[4];
  float hold[4];
  const float* gptr[4];
#pragma unroll
  for (int gq = 0; gq < 4; ++gq) {
    int lr = quad * 4 + gq;
    lens4[gq] = lengths[r0 + lr] - 1;
    hold[gq] = 0.f;
    gptr[gq] = gi_all + ((size_t)p * 25600 + (size_t)(r0 + lr) * LSEQ) * G3 + d;
  }

  // LDS addresses (swizzled): A-read per kk, h-write per gq
  int aoff[4];
#pragma unroll
  for (int kk = 0; kk < 4; ++kk)
    aoff[kk] = cN * 256 + (((quad * 8 + kk * 32) * 2) ^ ((cN & 7) << 4));
  int woff[4];
#pragma unroll
  for (int gq = 0; gq < 4; ++gq) {
    int lr = quad * 4 + gq;
    woff[gq] = lr * 256 + ((2 * d) ^ ((lr & 7) << 4));
  }

  // preload gi(t=0)
  float giaR[4], giaZ[4], giaN[4];
#pragma unroll
  for (int gq = 0; gq < 4; ++gq) {
    giaR[gq] = gptr[gq][0];
    giaZ[gq] = gptr[gq][HD];
    giaN[gq] = gptr[gq][2 * HD];
  }
  __syncthreads();

  for (int t = 0; t < LSEQ; ++t) {
    // software-pipelined gi prefetch for t+1 (last iter overreads into scratch; unused)
    float gbR[4], gbZ[4], gbN[4];
#pragma unroll
    for (int gq = 0; gq < 4; ++gq) {
      const float* gp = gptr[gq] + (size_t)(t + 1) * G3;
      gbR[gq] = gp[0]; gbZ[gq] = gp[HD]; gbN[gq] = gp[2 * HD];
    }
    const char* hb = (const char*)hlds[t & 1];
    f32x4 accR = {0.f, 0.f, 0.f, 0.f};
    f32x4 accZ = {0.f, 0.f, 0.f, 0.f};
    f32x4 accN = {0.f, 0.f, 0.f, 0.f};
#pragma unroll
    for (int kk = 0; kk < 4; ++kk) {
      short8 A = *(const short8*)(hb + aoff[kk]);
      accR = __builtin_amdgcn_mfma_f32_16x16x32_bf16(A, Br[kk], accR, 0, 0, 0);
      accZ = __builtin_amdgcn_mfma_f32_16x16x32_bf16(A, Bz[kk], accZ, 0, 0, 0);
      accN = __builtin_amdgcn_mfma_f32_16x16x32_bf16(A, Bn[kk], accN, 0, 0, 0);
    }
    char* hw = (char*)hlds[(t + 1) & 1];
#pragma unroll
    for (int gq = 0; gq < 4; ++gq) {
      float rg = fast_sigm(giaR[gq] + accR[gq] + bhr);
      float zg = fast_sigm(giaZ[gq] + accZ[gq] + bhz);
      float ng = fast_tanh(giaN[gq] + rg * (accN[gq] + bhn));
      float hnew = (1.f - zg) * ng + zg * hold[gq];
      hold[gq] = hnew;
      *(unsigned short*)(hw + woff[gq]) = f2bf(hnew);
      if (t == lens4[gq])
        ht_raw[((size_t)p * BSZ + r0 + quad * 4 + gq) * HD + d] = hnew;
    }
    __syncthreads();
#pragma unroll
    for (int gq = 0; gq < 4; ++gq) {
      giaR[gq] = gbR[gq]; giaZ[gq] = gbZ[gq]; giaN[gq] = gbN[gq];
    }
  }
}

// ---------------- layernorm ht in place + bf16 copy ------------------------
__global__ void ln_ht_kernel(float* __restrict__ ht,
                             const float* __restrict__ g2, const float* __restrict__ b2,
                             const float* __restrict__ g4, const float* __restrict__ b4,
                             unsigned short* __restrict__ hbf) {
  int w = threadIdx.x >> 6, l = threadIdx.x & 63;
  int r = blockIdx.x * 4 + w;
  if (r >= 2 * BSZ) return;
  const float* g = (r < BSZ) ? g2 : g4;
  const float* bb = (r < BSZ) ? b2 : b4;
  float a = ht[(size_t)r * HD + l];
  float b = ht[(size_t)r * HD + l + 64];
  float mu = wsum(a + b) * (1.f / HD);
  float v  = wsum(a * a + b * b) * (1.f / HD) - mu * mu;
  float rs = rsqrtf(v + 1e-5f);
  float va = (a - mu) * rs * g[l] + bb[l];
  float vb = (b - mu) * rs * g[l + 64] + bb[l + 64];
  ht[(size_t)r * HD + l]      = va;
  ht[(size_t)r * HD + l + 64] = vb;
  hbf[(size_t)r * HD + l]      = f2bf(va);
  hbf[(size_t)r * HD + l + 64] = f2bf(vb);
}

// ---------------- scores via MFMA bf16 -------------------------------------
__global__ __launch_bounds__(256) void scores_mfma_kernel(
    const unsigned short* __restrict__ hbf,
    const unsigned short* __restrict__ tbf,
    const unsigned short* __restrict__ cbf,
    const float* __restrict__ a1p, const float* __restrict__ a2p,
    float* __restrict__ out) {
  int wave = threadIdx.x >> 6;
  int lane = threadIdx.x & 63;
  int jt = blockIdx.x * 4 + wave;
  if (jt >= 3125) return;
  int j0 = jt * 16;
  int jcol = j0 + (lane & 15);
  int jl = (jcol < N_IT) ? jcol : (N_IT - 1);
  int ko = (lane >> 4) * 8;

  short8 B1[4], B2[4];
#pragma unroll
  for (int kk = 0; kk < 4; ++kk) {
    B1[kk] = *(const short8*)(tbf + (size_t)(jl + 1) * HD + kk * 32 + ko);
    B2[kk] = *(const short8*)(cbf + (size_t)(jl + 1) * HD + kk * 32 + ko);
  }
  float sa1 = sigmf(a1p[0]);
  float sa2 = sigmf(a2p[0]);
  const size_t S = (size_t)BSZ * N_IT;
  int rrow = (lane >> 4) * 4;
  bool wr = (jcol < N_IT);

  for (int r0 = 0; r0 < BSZ; r0 += 16) {
    int ra = r0 + (lane & 15);
    f32x4 acc1 = {0.f, 0.f, 0.f, 0.f}, acc2 = {0.f, 0.f, 0.f, 0.f};
#pragma unroll
    for (int kk = 0; kk < 4; ++kk) {
      short8 A1 = *(const short8*)(hbf + (size_t)ra * HD + kk * 32 + ko);
      short8 A2 = *(const short8*)(hbf + (size_t)(BSZ + ra) * HD + kk * 32 + ko);
      acc1 = __builtin_amdgcn_mfma_f32_16x16x32_bf16(A1, B1[kk], acc1, 0, 0, 0);
      acc2 = __builtin_amdgcn_mfma_f32_16x16x32_bf16(A2, B2[kk], acc2, 0, 0, 0);
    }
    if (wr) {
#pragma unroll
      for (int gq = 0; gq < 4; ++gq) {
        size_t o = (size_t)(r0 + rrow + gq) * N_IT + jcol;
        float s1 = acc1[gq], s2 = acc2[gq];
        out[o]         = sa1 * s1 + sa2 * s2;
        out[S + o]     = s1;
        out[2 * S + o] = s2;
      }
    }
  }
}

extern "C" void kernel_launch(void* const* d_in, const int* in_sizes, int n_in,
                              void* d_out, int out_size, void* d_ws, size_t ws_size,
                              hipStream_t stream) {
  const float* item_emb = (const float*)d_in[0];
  const float* prob_emb = (const float*)d_in[1];
  const float* W_cls    = (const float*)d_in[2];
  const float* a1       = (const float*)d_in[3];
  const float* a2       = (const float*)d_in[4];
  const float* Wih      = (const float*)d_in[5];
  const float* Whh      = (const float*)d_in[6];
  const float* bih      = (const float*)d_in[7];
  const float* bhh      = (const float*)d_in[8];
  const float* ln1_g = (const float*)d_in[9];
  const float* ln1_b = (const float*)d_in[10];
  const float* ln2_g = (const float*)d_in[11];
  const float* ln2_b = (const float*)d_in[12];
  const float* ln3_g = (const float*)d_in[13];
  const float* ln3_b = (const float*)d_in[14];
  const float* ln4_g = (const float*)d_in[15];
  const float* ln4_b = (const float*)d_in[16];
  const int* inp_sess = (const int*)d_in[19];
  const int* lengths  = (const int*)d_in[20];
  const int* adj      = (const int*)d_in[21];
  float* out = (float*)d_out;

  float* ws = (float*)d_ws;
  const size_t SZ_ROW = (size_t)N_IT * HD;
  float* xn  = ws;
  float* o1  = xn + SZ_ROW;
  float* o2  = o1 + SZ_ROW;
  float* tbl = o2 + SZ_ROW;
  float* ct  = tbl + (size_t)NI * HD;
  float* gi  = ct + (size_t)NI * HD;
  float* htb = gi + (size_t)2 * 25600 * G3;

  // aliases into dead regions:
  unsigned* xnb = (unsigned*)gi;               // bf16 normalized rows (dead before gi_kernel)
  unsigned short* tbf = (unsigned short*)xn;   // written by iv (xn dead after hop2)
  unsigned short* cbf = (unsigned short*)o2;   // written by cls (o2 dead after iv)
  unsigned short* hbf = (unsigned short*)o1;   // written by ln_ht (o1 dead after iv)

  int nb4 = (N_IT + 3) / 4;
  int nb4i = (NI + 3) / 4;

  norm_kernel<<<nb4, 256, 0, stream>>>(item_emb + HD, xn, xnb, N_IT);
  routing_kernel<<<nb4, 256, 0, stream>>>(xn, xnb, adj + MNB, o1);
  norm_kernel<<<nb4, 256, 0, stream>>>(o1, xn, xnb, N_IT);
  routing_kernel<<<nb4, 256, 0, stream>>>(xn, xnb, adj + MNB, o2);
  iv_kernel<<<nb4i, 256, 0, stream>>>(item_emb, o1, o2, ln1_g, ln1_b, tbl, tbf);
  cls_kernel<<<nb4i, 256, 0, stream>>>(prob_emb, W_cls, ln3_g, ln3_b, ct, cbf);
  gi_kernel<<<1600, 384, 0, stream>>>(tbl, ct, inp_sess, Wih, bih, gi);
  gru_mfma_kernel<<<64, 512, 0, stream>>>(gi, Whh, bhh, lengths, htb);
  ln_ht_kernel<<<256, 256, 0, stream>>>(htb, ln2_g, ln2_b, ln4_g, ln4_b, hbf);
  scores_mfma_kernel<<<(3125 + 3) / 4, 256, 0, stream>>>(hbf, tbf, cbf, a1, a2, out);
}

// Round 6
// 544.875 us; speedup vs baseline: 2.7458x; 1.2195x over previous
//
#include <hip/hip_runtime.h>
#include <hip/hip_bf16.h>

#define N_IT 49999
#define NI   50000
#define HD   128
#define MNB  16
#define BSZ  512
#define LSEQ 50
#define G3   384

typedef __attribute__((ext_vector_type(8))) short short8;
typedef __attribute__((ext_vector_type(4))) float f32x4;
typedef __attribute__((ext_vector_type(16))) float f32x16;

__device__ __forceinline__ float sigmf(float x) {
  return 1.f / (1.f + __expf(-x));
}
__device__ __forceinline__ float fast_sigm(float x) {
  return __fdividef(1.f, 1.f + __expf(-x));
}
__device__ __forceinline__ float fast_tanh(float x) {
  float e = __expf(-2.f * x);
  return (1.f - e) * __fdividef(1.f, 1.f + e);
}

__device__ __forceinline__ unsigned short f2bf(float f) {
  unsigned u = __float_as_uint(f);
  u += 0x7FFF + ((u >> 16) & 1);
  return (unsigned short)(u >> 16);
}

// ---- wave64 sum: 4 DPP stages (VALU) + ds_swizzle(xor16) + ds_bpermute(xor32)
template <int CTRL>
__device__ __forceinline__ float dppadd(float v) {
  int s = __builtin_amdgcn_update_dpp(__float_as_int(v), __float_as_int(v),
                                      CTRL, 0xF, 0xF, false);
  return v + __int_as_float(s);
}

__device__ __forceinline__ float wsum(float v) {
  v = dppadd<0xB1>(v);    // i^1
  v = dppadd<0x4E>(v);    // i^2
  v = dppadd<0x141>(v);   // i^7 (row_half_mirror)
  v = dppadd<0x140>(v);   // i^15 (row_mirror)
  v += __int_as_float(__builtin_amdgcn_ds_swizzle(__float_as_int(v), 0x401F)); // i^16
  int lane = threadIdx.x & 63;
  v += __int_as_float(__builtin_amdgcn_ds_bpermute(((lane ^ 32) << 2),
                                                   __float_as_int(v)));       // i^32
  return v;
}

// ---------------- normalize rows; lane owns d={2l,2l+1}; fp32 + bf16x2 out --
__global__ void norm_kernel(const float* __restrict__ x, float* __restrict__ o,
                            unsigned* __restrict__ ob, int n) {
  int w = threadIdx.x >> 6, l = threadIdx.x & 63;
  int r = blockIdx.x * 4 + w;
  if (r >= n) return;
  float2 xv = *(const float2*)(x + (size_t)r * HD + 2 * l);
  float sq = wsum(xv.x * xv.x + xv.y * xv.y);
  float inv = 1.f / fmaxf(sqrtf(sq), 1e-12f);
  float a = xv.x * inv, b = xv.y * inv;
  *(float2*)(o + (size_t)r * HD + 2 * l) = make_float2(a, b);
  ob[(size_t)r * 64 + l] = (unsigned)f2bf(a) | ((unsigned)f2bf(b) << 16);
}

// ---------------- routing: one wave per node, z in registers ---------------
__global__ __launch_bounds__(256) void routing_kernel(
    const float* __restrict__ xn, const unsigned* __restrict__ xnb,
    const int* __restrict__ adj, float* __restrict__ out) {
  int w = threadIdx.x >> 6, l = threadIdx.x & 63;
  int n = blockIdx.x * 4 + w;
  if (n >= N_IT) return;

  float z0[MNB], z1[MNB];
#pragma unroll
  for (int m = 0; m < MNB; ++m) {
    int idx = adj[n * MNB + m] - 1;
    unsigned v = xnb[(size_t)idx * 64 + l];
    z0[m] = __int_as_float((v & 0xFFFFu) << 16);
    z1[m] = __int_as_float((v >> 16) << 16);
  }
  float2 xv = *(const float2*)(xn + (size_t)n * HD + 2 * l);
  float xs0 = xv.x, xs1 = xv.y;

  float u0 = 0.f, u1 = 0.f;
#pragma unroll
  for (int m = 0; m < MNB; ++m) { u0 += z0[m]; u1 += z1[m]; }
  u0 = u0 * (1.f / MNB) + xs0;
  u1 = u1 * (1.f / MNB) + xs1;

  for (int it = 0; it < 3; ++it) {
    float sq = wsum(u0 * u0 + u1 * u1);
    float s = (sq / (sq + 1.f)) / fmaxf(sqrtf(sq), 1e-12f);
    u0 *= s; u1 *= s;
    float lg[MNB];
#pragma unroll
    for (int m = 0; m < MNB; ++m)
      lg[m] = wsum(z0[m] * u0 + z1[m] * u1);
    float se = 0.f;
#pragma unroll
    for (int m = 0; m < MNB; ++m) { lg[m] = __expf(lg[m]); se += lg[m]; }
    float inv = 1.f / se;
    u0 = xs0; u1 = xs1;
#pragma unroll
    for (int m = 0; m < MNB; ++m) {
      float p = lg[m] * inv;
      u0 += z0[m] * p;
      u1 += z1[m] * p;
    }
  }
  *(float2*)(out + (size_t)n * HD + 2 * l) = make_float2(u0, u1);
}

// ---------------- iv table (bf16 only): row0=0; rows 1..: LN1(x0+o1+o2) ----
__global__ void iv_kernel(const float* __restrict__ item_emb,
                          const float* __restrict__ o1, const float* __restrict__ o2,
                          const float* __restrict__ g, const float* __restrict__ bb,
                          unsigned short* __restrict__ tbf) {
  int w = threadIdx.x >> 6, l = threadIdx.x & 63;
  int r = blockIdx.x * 4 + w;
  if (r >= NI) return;
  if (r == 0) {
    tbf[l] = 0; tbf[l + 64] = 0;
    return;
  }
  size_t pr = (size_t)(r - 1) * HD;
  float a = item_emb[(size_t)r * HD + l]      + o1[pr + l]      + o2[pr + l];
  float b = item_emb[(size_t)r * HD + l + 64] + o1[pr + l + 64] + o2[pr + l + 64];
  float mu = wsum(a + b) * (1.f / HD);
  float v  = wsum(a * a + b * b) * (1.f / HD) - mu * mu;
  float rs = rsqrtf(v + 1e-5f);
  float va = (a - mu) * rs * g[l] + bb[l];
  float vb = (b - mu) * rs * g[l + 64] + bb[l + 64];
  tbf[(size_t)r * HD + l]      = f2bf(va);
  tbf[(size_t)r * HD + l + 64] = f2bf(vb);
}

// ---------------- cls table (bf16 only): LN3(prob_emb @ W_cls.T) -----------
__global__ void cls_kernel(const float* __restrict__ prob, const float* __restrict__ Wc,
                           const float* __restrict__ g, const float* __restrict__ bb,
                           unsigned short* __restrict__ cbf) {
  int w = threadIdx.x >> 6, l = threadIdx.x & 63;
  int r = blockIdx.x * 4 + w;
  if (r >= NI) return;
  float p[10];
#pragma unroll
  for (int k = 0; k < 10; ++k) p[k] = prob[(size_t)r * 10 + k];
  float a = 0.f, b = 0.f;
#pragma unroll
  for (int k = 0; k < 10; ++k) {
    a += p[k] * Wc[l * 10 + k];
    b += p[k] * Wc[(l + 64) * 10 + k];
  }
  float mu = wsum(a + b) * (1.f / HD);
  float v  = wsum(a * a + b * b) * (1.f / HD) - mu * mu;
  float rs = rsqrtf(v + 1e-5f);
  float va = (a - mu) * rs * g[l] + bb[l];
  float vb = (b - mu) * rs * g[l + 64] + bb[l + 64];
  cbf[(size_t)r * HD + l]      = f2bf(va);
  cbf[(size_t)r * HD + l + 64] = f2bf(vb);
}

// ---------------- Wih -> bf16 ----------------------------------------------
__global__ void wbf_kernel(const float* __restrict__ Wih,
                           unsigned short* __restrict__ wbf) {
  int i = blockIdx.x * 256 + threadIdx.x;
  if (i < 3 * HD * HD) wbf[i] = f2bf(Wih[i]);
}

// ---------------- gi via MFMA: gi[row][j] = dot(x_row, Wih[j]) (no bias) ---
// block 256 = 4 waves; 16 rows x 384 gates; wave w owns 6 j-tiles of 16.
__global__ __launch_bounds__(256) void gi2_kernel(
    const unsigned short* __restrict__ tbf, const unsigned short* __restrict__ cbf,
    const int* __restrict__ sess, const unsigned short* __restrict__ wbf,
    float* __restrict__ gi) {
  __shared__ int sidx[16];
  int tid = threadIdx.x;
  int row0 = blockIdx.x * 16;
  if (tid < 16) sidx[tid] = sess[(row0 + tid) % 25600];
  __syncthreads();
  const unsigned short* src = (row0 < 25600) ? tbf : cbf;
  int w = tid >> 6, lane = tid & 63;
  int rloc = lane & 15, quad = lane >> 4;
  int arow = sidx[rloc];
  int ko = quad * 8;
  short8 A[4];
#pragma unroll
  for (int kk = 0; kk < 4; ++kk)
    A[kk] = *(const short8*)(src + (size_t)arow * HD + kk * 32 + ko);
  float* gout = gi + (size_t)row0 * G3;
#pragma unroll
  for (int s = 0; s < 6; ++s) {
    int jt = w * 6 + s;
    int j = jt * 16 + rloc;
    f32x4 acc = {0.f, 0.f, 0.f, 0.f};
#pragma unroll
    for (int kk = 0; kk < 4; ++kk) {
      short8 B = *(const short8*)(wbf + (size_t)j * HD + kk * 32 + ko);
      acc = __builtin_amdgcn_mfma_f32_16x16x32_bf16(A[kk], B, acc, 0, 0, 0);
    }
#pragma unroll
    for (int q = 0; q < 4; ++q)
      gout[(size_t)(quad * 4 + q) * G3 + jt * 16 + rloc] = acc[q];
  }
}

// ---------------- GRU recurrence via MFMA ----------------------------------
// 64 blocks: p = blk>>5, row-tile = blk&31 (16 rows). 512 threads = 8 waves.
// Wave w owns gate-tiles {16w, 128+16w, 256+16w}; elementwise stays in regs.
// h: bf16 in double-buffered swizzled LDS; fp32 h in regs. gi is raw (no bih).
__global__ __launch_bounds__(512) void gru_mfma_kernel(
    const float* __restrict__ gi_all, const float* __restrict__ Whh,
    const float* __restrict__ bih, const float* __restrict__ bhh,
    const int* __restrict__ lengths, float* __restrict__ ht_raw) {
  __shared__ unsigned short hlds[2][16 * HD];  // 8 KB
  int tid = threadIdx.x;
  int lane = tid & 63;
  int w = tid >> 6;
  int p = blockIdx.x >> 5;
  int r0 = (blockIdx.x & 31) * 16;
  int cN = lane & 15;
  int quad = lane >> 4;
  int d = w * 16 + cN;

  {
    int* hz = (int*)hlds;
    for (int i = tid; i < 2 * 16 * HD / 2; i += 512) hz[i] = 0;
  }

  short8 Br[4], Bz[4], Bn[4];
#pragma unroll
  for (int kk = 0; kk < 4; ++kk) {
    int kbase = quad * 8 + kk * 32;
    const float* wr_ = Whh + (size_t)d * HD + kbase;
    const float* wz_ = Whh + (size_t)(128 + d) * HD + kbase;
    const float* wn_ = Whh + (size_t)(256 + d) * HD + kbase;
    float4 r0v = *(const float4*)wr_, r1v = *(const float4*)(wr_ + 4);
    float4 z0v = *(const float4*)wz_, z1v = *(const float4*)(wz_ + 4);
    float4 n0v = *(const float4*)wn_, n1v = *(const float4*)(wn_ + 4);
    short8 br, bz, bn;
    br[0]=(short)f2bf(r0v.x); br[1]=(short)f2bf(r0v.y); br[2]=(short)f2bf(r0v.z); br[3]=(short)f2bf(r0v.w);
    br[4]=(short)f2bf(r1v.x); br[5]=(short)f2bf(r1v.y); br[6]=(short)f2bf(r1v.z); br[7]=(short)f2bf(r1v.w);
    bz[0]=(short)f2bf(z0v.x); bz[1]=(short)f2bf(z0v.y); bz[2]=(short)f2bf(z0v.z); bz[3]=(short)f2bf(z0v.w);
    bz[4]=(short)f2bf(z1v.x); bz[5]=(short)f2bf(z1v.y); bz[6]=(short)f2bf(z1v.z); bz[7]=(short)f2bf(z1v.w);
    bn[0]=(short)f2bf(n0v.x); bn[1]=(short)f2bf(n0v.y); bn[2]=(short)f2bf(n0v.z); bn[3]=(short)f2bf(n0v.w);
    bn[4]=(short)f2bf(n1v.x); bn[5]=(short)f2bf(n1v.y); bn[6]=(short)f2bf(n1v.z); bn[7]=(short)f2bf(n1v.w);
    Br[kk] = br; Bz[kk] = bz; Bn[kk] = bn;
  }
  float cr = bhh[d] + bih[d];
  float cz = bhh[128 + d] + bih[128 + d];
  float bhn = bhh[256 + d], bin = bih[256 + d];

  int lens4[4];
  float hold[4];
  const float* gptr[4];
#pragma unroll
  for (int gq = 0; gq < 4; ++gq) {
    int lr = quad * 4 + gq;
    lens4[gq] = lengths[r0 + lr] - 1;
    hold[gq] = 0.f;
    gptr[gq] = gi_all + ((size_t)p * 25600 + (size_t)(r0 + lr) * LSEQ) * G3 + d;
  }

  int aoff[4];
#pragma unroll
  for (int kk = 0; kk < 4; ++kk)
    aoff[kk] = cN * 256 + (((quad * 8 + kk * 32) * 2) ^ ((cN & 7) << 4));
  int woff[4];
#pragma unroll
  for (int gq = 0; gq < 4; ++gq) {
    int lr = quad * 4 + gq;
    woff[gq] = lr * 256 + ((2 * d) ^ ((lr & 7) << 4));
  }

  float giaR[4], giaZ[4], giaN[4];
#pragma unroll
  for (int gq = 0; gq < 4; ++gq) {
    giaR[gq] = gptr[gq][0];
    giaZ[gq] = gptr[gq][HD];
    giaN[gq] = gptr[gq][2 * HD];
  }
  __syncthreads();

  for (int t = 0; t < LSEQ; ++t) {
    float gbR[4], gbZ[4], gbN[4];
#pragma unroll
    for (int gq = 0; gq < 4; ++gq) {
      const float* gp = gptr[gq] + (size_t)(t + 1) * G3;
      gbR[gq] = gp[0]; gbZ[gq] = gp[HD]; gbN[gq] = gp[2 * HD];
    }
    const char* hb = (const char*)hlds[t & 1];
    f32x4 accR = {0.f, 0.f, 0.f, 0.f};
    f32x4 accZ = {0.f, 0.f, 0.f, 0.f};
    f32x4 accN = {0.f, 0.f, 0.f, 0.f};
#pragma unroll
    for (int kk = 0; kk < 4; ++kk) {
      short8 A = *(const short8*)(hb + aoff[kk]);
      accR = __builtin_amdgcn_mfma_f32_16x16x32_bf16(A, Br[kk], accR, 0, 0, 0);
      accZ = __builtin_amdgcn_mfma_f32_16x16x32_bf16(A, Bz[kk], accZ, 0, 0, 0);
      accN = __builtin_amdgcn_mfma_f32_16x16x32_bf16(A, Bn[kk], accN, 0, 0, 0);
    }
    char* hw = (char*)hlds[(t + 1) & 1];
#pragma unroll
    for (int gq = 0; gq < 4; ++gq) {
      float rg = fast_sigm(giaR[gq] + accR[gq] + cr);
      float zg = fast_sigm(giaZ[gq] + accZ[gq] + cz);
      float ng = fast_tanh(giaN[gq] + bin + rg * (accN[gq] + bhn));
      float hnew = (1.f - zg) * ng + zg * hold[gq];
      hold[gq] = hnew;
      *(unsigned short*)(hw + woff[gq]) = f2bf(hnew);
      if (t == lens4[gq])
        ht_raw[((size_t)p * BSZ + r0 + quad * 4 + gq) * HD + d] = hnew;
    }
    __syncthreads();
#pragma unroll
    for (int gq = 0; gq < 4; ++gq) {
      giaR[gq] = gbR[gq]; giaZ[gq] = gbZ[gq]; giaN[gq] = gbN[gq];
    }
  }
}

// ---------------- layernorm ht + bf16 copy ---------------------------------
__global__ void ln_ht_kernel(float* __restrict__ ht,
                             const float* __restrict__ g2, const float* __restrict__ b2,
                             const float* __restrict__ g4, const float* __restrict__ b4,
                             unsigned short* __restrict__ hbf) {
  int w = threadIdx.x >> 6, l = threadIdx.x & 63;
  int r = blockIdx.x * 4 + w;
  if (r >= 2 * BSZ) return;
  const float* g = (r < BSZ) ? g2 : g4;
  const float* bb = (r < BSZ) ? b2 : b4;
  float a = ht[(size_t)r * HD + l];
  float b = ht[(size_t)r * HD + l + 64];
  float mu = wsum(a + b) * (1.f / HD);
  float v  = wsum(a * a + b * b) * (1.f / HD) - mu * mu;
  float rs = rsqrtf(v + 1e-5f);
  float va = (a - mu) * rs * g[l] + bb[l];
  float vb = (b - mu) * rs * g[l + 64] + bb[l + 64];
  hbf[(size_t)r * HD + l]      = f2bf(va);
  hbf[(size_t)r * HD + l + 64] = f2bf(vb);
}

// ---------------- scores: 32x32x16 MFMA + LDS-staged contiguous stores -----
// block 512 thr (8 waves): tile 32 rows x 256 items. wave w owns j-subtile w.
// grid: (strip 0..195) * 16 + row-block. Stage s1/s2 in LDS (64KB), then
// cooperative dword stores: consecutive threads -> consecutive addresses.
#define JW 256
__global__ __launch_bounds__(512) void scores2_kernel(
    const unsigned short* __restrict__ hbf,
    const unsigned short* __restrict__ tbf,
    const unsigned short* __restrict__ cbf,
    const float* __restrict__ a1p, const float* __restrict__ a2p,
    float* __restrict__ out) {
  __shared__ float s1l[32 * JW];
  __shared__ float s2l[32 * JW];
  int tid = threadIdx.x;
  int w = tid >> 6, lane = tid & 63;
  int strip = blockIdx.x >> 4;
  int r0b = (blockIdx.x & 15) * 32;
  int j0 = strip * JW;
  int jc = j0 + w * 32 + (lane & 31);
  int jl = (jc < N_IT) ? jc : (N_IT - 1);
  int koA = (lane >> 5) * 8;

  f32x16 acc1 = {0.f}, acc2 = {0.f};
  const unsigned short* h1p = hbf + (size_t)(r0b + (lane & 31)) * HD + koA;
  const unsigned short* h2p = h1p + (size_t)BSZ * HD;
  const unsigned short* b1p = tbf + (size_t)(jl + 1) * HD + koA;
  const unsigned short* b2p = cbf + (size_t)(jl + 1) * HD + koA;
#pragma unroll
  for (int kk = 0; kk < 8; ++kk) {
    short8 A1 = *(const short8*)(h1p + kk * 16);
    short8 A2 = *(const short8*)(h2p + kk * 16);
    short8 B1 = *(const short8*)(b1p + kk * 16);
    short8 B2 = *(const short8*)(b2p + kk * 16);
    acc1 = __builtin_amdgcn_mfma_f32_32x32x16_bf16(A1, B1, acc1, 0, 0, 0);
    acc2 = __builtin_amdgcn_mfma_f32_32x32x16_bf16(A2, B2, acc2, 0, 0, 0);
  }
  int colb = w * 32 + (lane & 31);
#pragma unroll
  for (int q = 0; q < 16; ++q) {
    int row = (q & 3) + 8 * (q >> 2) + 4 * (lane >> 5);
    s1l[row * JW + colb] = acc1[q];
    s2l[row * JW + colb] = acc2[q];
  }
  __syncthreads();

  float sa1 = sigmf(a1p[0]);
  float sa2 = sigmf(a2p[0]);
  const size_t S = (size_t)BSZ * N_IT;
#pragma unroll
  for (int pss = 0; pss < 16; ++pss) {
    int idx = pss * 512 + tid;
    int row = idx >> 8;
    int jlc = idx & 255;
    int jg = j0 + jlc;
    if (jg < N_IT) {
      float s1 = s1l[idx];
      float s2 = s2l[idx];
      size_t o = (size_t)(r0b + row) * N_IT + jg;
      out[o]         = sa1 * s1 + sa2 * s2;
      out[S + o]     = s1;
      out[2 * S + o] = s2;
    }
  }
}

extern "C" void kernel_launch(void* const* d_in, const int* in_sizes, int n_in,
                              void* d_out, int out_size, void* d_ws, size_t ws_size,
                              hipStream_t stream) {
  const float* item_emb = (const float*)d_in[0];
  const float* prob_emb = (const float*)d_in[1];
  const float* W_cls    = (const float*)d_in[2];
  const float* a1       = (const float*)d_in[3];
  const float* a2       = (const float*)d_in[4];
  const float* Wih      = (const float*)d_in[5];
  const float* Whh      = (const float*)d_in[6];
  const float* bih      = (const float*)d_in[7];
  const float* bhh      = (const float*)d_in[8];
  const float* ln1_g = (const float*)d_in[9];
  const float* ln1_b = (const float*)d_in[10];
  const float* ln2_g = (const float*)d_in[11];
  const float* ln2_b = (const float*)d_in[12];
  const float* ln3_g = (const float*)d_in[13];
  const float* ln3_b = (const float*)d_in[14];
  const float* ln4_g = (const float*)d_in[15];
  const float* ln4_b = (const float*)d_in[16];
  const int* inp_sess = (const int*)d_in[19];
  const int* lengths  = (const int*)d_in[20];
  const int* adj      = (const int*)d_in[21];
  float* out = (float*)d_out;

  float* ws = (float*)d_ws;
  const size_t SZ_ROW = (size_t)N_IT * HD;
  float* xn  = ws;
  float* o1  = xn + SZ_ROW;
  float* o2  = o1 + SZ_ROW;
  float* gi  = o2 + SZ_ROW + 2 * (size_t)NI * HD;   // after (now unused) tbl/ct slots
  float* htb = gi + (size_t)2 * 25600 * G3;

  // aliases into dead regions:
  unsigned* xnb = (unsigned*)gi;                    // dead before gi2 writes gi
  unsigned short* tbf = (unsigned short*)xn;        // written by iv (xn dead after hop2)
  unsigned short* cbf = (unsigned short*)o2;        // written by cls (o2 dead after iv)
  unsigned short* hbf = (unsigned short*)o1;        // written by ln_ht (o1 dead after iv)
  unsigned short* wbf = (unsigned short*)(o2 + 3400000);  // past cbf (3.2M floats)

  int nb4 = (N_IT + 3) / 4;
  int nb4i = (NI + 3) / 4;

  norm_kernel<<<nb4, 256, 0, stream>>>(item_emb + HD, xn, xnb, N_IT);
  routing_kernel<<<nb4, 256, 0, stream>>>(xn, xnb, adj + MNB, o1);
  norm_kernel<<<nb4, 256, 0, stream>>>(o1, xn, xnb, N_IT);
  routing_kernel<<<nb4, 256, 0, stream>>>(xn, xnb, adj + MNB, o2);
  iv_kernel<<<nb4i, 256, 0, stream>>>(item_emb, o1, o2, ln1_g, ln1_b, tbf);
  cls_kernel<<<nb4i, 256, 0, stream>>>(prob_emb, W_cls, ln3_g, ln3_b, cbf);
  wbf_kernel<<<192, 256, 0, stream>>>(Wih, wbf);
  gi2_kernel<<<3200, 256, 0, stream>>>(tbf, cbf, inp_sess, wbf, gi);
  gru_mfma_kernel<<<64, 512, 0, stream>>>(gi, Whh, bih, bhh, lengths, htb);
  ln_ht_kernel<<<256, 256, 0, stream>>>(htb, ln2_g, ln2_b, ln4_g, ln4_b, hbf);
  scores2_kernel<<<196 * 16, 512, 0, stream>>>(hbf, tbf, cbf, a1, a2, out);
}

// Round 7
// 419.538 us; speedup vs baseline: 3.5661x; 1.2987x over previous
//
#include <hip/hip_runtime.h>
#include <hip/hip_bf16.h>

#define N_IT 49999
#define NI   50000
#define HD   128
#define MNB  16
#define BSZ  512
#define LSEQ 50
#define G3   384

typedef __attribute__((ext_vector_type(8))) short short8;
typedef __attribute__((ext_vector_type(4))) float f32x4;
typedef __attribute__((ext_vector_type(16))) float f32x16;

__device__ __forceinline__ float sigmf(float x) {
  return 1.f / (1.f + __expf(-x));
}
__device__ __forceinline__ float fast_sigm(float x) {
  return __fdividef(1.f, 1.f + __expf(-x));
}
__device__ __forceinline__ float fast_tanh(float x) {
  float e = __expf(-2.f * x);
  return (1.f - e) * __fdividef(1.f, 1.f + e);
}

__device__ __forceinline__ unsigned short f2bf(float f) {
  unsigned u = __float_as_uint(f);
  u += 0x7FFF + ((u >> 16) & 1);
  return (unsigned short)(u >> 16);
}

// ---- DPP / swizzle butterfly helpers --------------------------------------
template <int CTRL>
__device__ __forceinline__ float dppadd(float v) {
  int s = __builtin_amdgcn_update_dpp(__float_as_int(v), __float_as_int(v),
                                      CTRL, 0xF, 0xF, false);
  return v + __int_as_float(s);
}
template <int MASK>
__device__ __forceinline__ float swzadd(float v) {
  return v + __int_as_float(__builtin_amdgcn_ds_swizzle(__float_as_int(v), MASK));
}
__device__ __forceinline__ float bp32add(float v) {
  int lane = threadIdx.x & 63;
  return v + __int_as_float(__builtin_amdgcn_ds_bpermute(((lane ^ 32) << 2),
                                                         __float_as_int(v)));
}

__device__ __forceinline__ float wsum(float v) {
  v = dppadd<0xB1>(v);    // i^1
  v = dppadd<0x4E>(v);    // i^2
  v = dppadd<0x141>(v);   // i^7 (row_half_mirror)
  v = dppadd<0x140>(v);   // i^15 (row_mirror)
  v = swzadd<0x401F>(v);  // i^16
  v = bp32add(v);         // i^32
  return v;
}

// ---------------- normalize rows; lane owns d={2l,2l+1}; fp32 + bf16x2 out --
__global__ void norm_kernel(const float* __restrict__ x, float* __restrict__ o,
                            unsigned* __restrict__ ob, int n) {
  int w = threadIdx.x >> 6, l = threadIdx.x & 63;
  int r = blockIdx.x * 4 + w;
  if (r >= n) return;
  float2 xv = *(const float2*)(x + (size_t)r * HD + 2 * l);
  float sq = wsum(xv.x * xv.x + xv.y * xv.y);
  float inv = 1.f / fmaxf(sqrtf(sq), 1e-12f);
  float a = xv.x * inv, b = xv.y * inv;
  *(float2*)(o + (size_t)r * HD + 2 * l) = make_float2(a, b);
  ob[(size_t)r * 64 + l] = (unsigned)f2bf(a) | ((unsigned)f2bf(b) << 16);
}

// ---------------- routing v3: Gram-matrix + MFMA ---------------------------
// One wave per node. u always = xs + Z^T c, so precompute G=Z Z^T and b=Z xs
// via 8 MFMAs (same gathered regs as both operands), then 3 iterations of
// 16-dim algebra: lg = s(b + Gc), sq = 1 + 2 c.b + c.Gc, softmax, c<-p.
// z staged once in XOR-swizzled LDS for the final per-dim update.
__global__ __launch_bounds__(256) void routing_kernel(
    const float* __restrict__ xn, const unsigned* __restrict__ xnb,
    const int* __restrict__ adj, float* __restrict__ out) {
  __shared__ char zsh[4][4096];
  int tid = threadIdx.x;
  int w = tid >> 6, lane = tid & 63;
  int n = blockIdx.x * 4 + w;
  if (n >= N_IT) return;
  int m = lane & 15, quad = lane >> 4;
  const unsigned short* xb16 = (const unsigned short*)xnb;

  int idx = adj[n * MNB + m] - 1;
  const unsigned short* zrow = xb16 + (size_t)idx * HD;
  const unsigned short* xrow = xb16 + (size_t)n * HD;
  short8 zf[4], xf[4];
#pragma unroll
  for (int kk = 0; kk < 4; ++kk) {
    zf[kk] = *(const short8*)(zrow + kk * 32 + quad * 8);
    xf[kk] = *(const short8*)(xrow + kk * 32 + quad * 8);
  }
  // G[m][k] and b[m]; D-layout: lane holds row (quad*4+q), col (lane&15)
  f32x4 Gf = {0.f, 0.f, 0.f, 0.f}, Bv = {0.f, 0.f, 0.f, 0.f};
#pragma unroll
  for (int kk = 0; kk < 4; ++kk) {
    Gf = __builtin_amdgcn_mfma_f32_16x16x32_bf16(zf[kk], zf[kk], Gf, 0, 0, 0);
    Bv = __builtin_amdgcn_mfma_f32_16x16x32_bf16(zf[kk], xf[kk], Bv, 0, 0, 0);
  }
  // stage z in LDS (linear d*2 bytes, XOR-swizzled by row) for final update
  char* zb = zsh[w] + m * 256;
#pragma unroll
  for (int kk = 0; kk < 4; ++kk)
    *(short8*)(zb + ((kk * 64 + quad * 16) ^ ((m & 7) << 4))) = zf[kk];

  // c in row-form: pc[q] = c[quad*4+q] (duplicated across the 16 cols)
  float pc0 = 0.0625f, pc1 = 0.0625f, pc2 = 0.0625f, pc3 = 0.0625f;
  int msel = lane & 3;
  // source lane for col-form pull: holds p[(l'>>4)*4 + (l'&3)] == p[lane&15]
  int cjaddr = (((lane >> 2) & 3) << 4 | (lane & 3)) << 2;

#pragma unroll
  for (int it = 0; it < 3; ++it) {
    float selv = (msel == 0) ? pc0 : (msel == 1) ? pc1 : (msel == 2) ? pc2 : pc3;
    float cj = __int_as_float(
        __builtin_amdgcn_ds_bpermute(cjaddr, __float_as_int(selv)));
    // (G c)[m]: per-col partial then butterfly over the 16 cols
    float g0 = Gf[0] * cj, g1 = Gf[1] * cj, g2 = Gf[2] * cj, g3 = Gf[3] * cj;
    g0 = dppadd<0xB1>(g0); g1 = dppadd<0xB1>(g1); g2 = dppadd<0xB1>(g2); g3 = dppadd<0xB1>(g3);
    g0 = dppadd<0x4E>(g0); g1 = dppadd<0x4E>(g1); g2 = dppadd<0x4E>(g2); g3 = dppadd<0x4E>(g3);
    g0 = swzadd<0x101F>(g0); g1 = swzadd<0x101F>(g1); g2 = swzadd<0x101F>(g2); g3 = swzadd<0x101F>(g3);
    g0 = swzadd<0x201F>(g0); g1 = swzadd<0x201F>(g1); g2 = swzadd<0x201F>(g2); g3 = swzadd<0x201F>(g3);
    // sq = ||u_pre||^2 = 1 + 2 c.b + c.Gc  (reduce own 4 m, then row-groups)
    float t1 = pc0 * g0 + pc1 * g1 + pc2 * g2 + pc3 * g3;
    float t2 = pc0 * Bv[0] + pc1 * Bv[1] + pc2 * Bv[2] + pc3 * Bv[3];
    t1 = swzadd<0x401F>(t1); t1 = bp32add(t1);
    t2 = swzadd<0x401F>(t2); t2 = bp32add(t2);
    float sq = fmaxf(1.f + 2.f * t2 + t1, 0.f);
    float s = (sq / (sq + 1.f)) / fmaxf(sqrtf(sq), 1e-12f);
    // softmax over m (|lg| < 1, no max-sub needed)
    float e0 = __expf(s * (Bv[0] + g0));
    float e1 = __expf(s * (Bv[1] + g1));
    float e2 = __expf(s * (Bv[2] + g2));
    float e3 = __expf(s * (Bv[3] + g3));
    float se = e0 + e1 + e2 + e3;
    se = swzadd<0x401F>(se); se = bp32add(se);
    float inv = __fdividef(1.f, se);
    pc0 = e0 * inv; pc1 = e1 * inv; pc2 = e2 * inv; pc3 = e3 * inv;
  }
  // final: u = xs + sum_m p[m] z[m]  (per-dim layout from LDS)
  float selv = (msel == 0) ? pc0 : (msel == 1) ? pc1 : (msel == 2) ? pc2 : pc3;
  float2 xv = *(const float2*)(xn + (size_t)n * HD + 2 * lane);
  float u0 = xv.x, u1 = xv.y;
#pragma unroll
  for (int mm = 0; mm < MNB; ++mm) {
    int srcl = ((((mm >> 2) << 4) | (mm & 3)) << 2);
    float pm = __int_as_float(
        __builtin_amdgcn_ds_bpermute(srcl, __float_as_int(selv)));
    unsigned zv = *(const unsigned*)(zsh[w] + mm * 256 +
                                     ((4 * lane) ^ ((mm & 7) << 4)));
    float z0 = __int_as_float((zv & 0xFFFFu) << 16);
    float z1 = __int_as_float((zv >> 16) << 16);
    u0 += z0 * pm;
    u1 += z1 * pm;
  }
  *(float2*)(out + (size_t)n * HD + 2 * lane) = make_float2(u0, u1);
}

// ---------------- iv table (bf16 only): row0=0; rows 1..: LN1(x0+o1+o2) ----
__global__ void iv_kernel(const float* __restrict__ item_emb,
                          const float* __restrict__ o1, const float* __restrict__ o2,
                          const float* __restrict__ g, const float* __restrict__ bb,
                          unsigned short* __restrict__ tbf) {
  int w = threadIdx.x >> 6, l = threadIdx.x & 63;
  int r = blockIdx.x * 4 + w;
  if (r >= NI) return;
  if (r == 0) {
    tbf[l] = 0; tbf[l + 64] = 0;
    return;
  }
  size_t pr = (size_t)(r - 1) * HD;
  float a = item_emb[(size_t)r * HD + l]      + o1[pr + l]      + o2[pr + l];
  float b = item_emb[(size_t)r * HD + l + 64] + o1[pr + l + 64] + o2[pr + l + 64];
  float mu = wsum(a + b) * (1.f / HD);
  float v  = wsum(a * a + b * b) * (1.f / HD) - mu * mu;
  float rs = rsqrtf(v + 1e-5f);
  float va = (a - mu) * rs * g[l] + bb[l];
  float vb = (b - mu) * rs * g[l + 64] + bb[l + 64];
  tbf[(size_t)r * HD + l]      = f2bf(va);
  tbf[(size_t)r * HD + l + 64] = f2bf(vb);
}

// ---------------- cls table (bf16 only): LN3(prob_emb @ W_cls.T) -----------
__global__ void cls_kernel(const float* __restrict__ prob, const float* __restrict__ Wc,
                           const float* __restrict__ g, const float* __restrict__ bb,
                           unsigned short* __restrict__ cbf) {
  int w = threadIdx.x >> 6, l = threadIdx.x & 63;
  int r = blockIdx.x * 4 + w;
  if (r >= NI) return;
  float p[10];
#pragma unroll
  for (int k = 0; k < 10; ++k) p[k] = prob[(size_t)r * 10 + k];
  float a = 0.f, b = 0.f;
#pragma unroll
  for (int k = 0; k < 10; ++k) {
    a += p[k] * Wc[l * 10 + k];
    b += p[k] * Wc[(l + 64) * 10 + k];
  }
  float mu = wsum(a + b) * (1.f / HD);
  float v  = wsum(a * a + b * b) * (1.f / HD) - mu * mu;
  float rs = rsqrtf(v + 1e-5f);
  float va = (a - mu) * rs * g[l] + bb[l];
  float vb = (b - mu) * rs * g[l + 64] + bb[l + 64];
  cbf[(size_t)r * HD + l]      = f2bf(va);
  cbf[(size_t)r * HD + l + 64] = f2bf(vb);
}

// ---------------- Wih -> bf16 ----------------------------------------------
__global__ void wbf_kernel(const float* __restrict__ Wih,
                           unsigned short* __restrict__ wbf) {
  int i = blockIdx.x * 256 + threadIdx.x;
  if (i < 3 * HD * HD) wbf[i] = f2bf(Wih[i]);
}

// ---------------- gi via MFMA: gi[row][j] = dot(x_row, Wih[j]) (no bias) ---
__global__ __launch_bounds__(256) void gi2_kernel(
    const unsigned short* __restrict__ tbf, const unsigned short* __restrict__ cbf,
    const int* __restrict__ sess, const unsigned short* __restrict__ wbf,
    float* __restrict__ gi) {
  __shared__ int sidx[16];
  int tid = threadIdx.x;
  int row0 = blockIdx.x * 16;
  if (tid < 16) sidx[tid] = sess[(row0 + tid) % 25600];
  __syncthreads();
  const unsigned short* src = (row0 < 25600) ? tbf : cbf;
  int w = tid >> 6, lane = tid & 63;
  int rloc = lane & 15, quad = lane >> 4;
  int arow = sidx[rloc];
  int ko = quad * 8;
  short8 A[4];
#pragma unroll
  for (int kk = 0; kk < 4; ++kk)
    A[kk] = *(const short8*)(src + (size_t)arow * HD + kk * 32 + ko);
  float* gout = gi + (size_t)row0 * G3;
#pragma unroll
  for (int s = 0; s < 6; ++s) {
    int jt = w * 6 + s;
    int j = jt * 16 + rloc;
    f32x4 acc = {0.f, 0.f, 0.f, 0.f};
#pragma unroll
    for (int kk = 0; kk < 4; ++kk) {
      short8 B = *(const short8*)(wbf + (size_t)j * HD + kk * 32 + ko);
      acc = __builtin_amdgcn_mfma_f32_16x16x32_bf16(A[kk], B, acc, 0, 0, 0);
    }
#pragma unroll
    for (int q = 0; q < 4; ++q)
      gout[(size_t)(quad * 4 + q) * G3 + jt * 16 + rloc] = acc[q];
  }
}

// ---------------- GRU recurrence via MFMA ----------------------------------
__global__ __launch_bounds__(512) void gru_mfma_kernel(
    const float* __restrict__ gi_all, const float* __restrict__ Whh,
    const float* __restrict__ bih, const float* __restrict__ bhh,
    const int* __restrict__ lengths, float* __restrict__ ht_raw) {
  __shared__ unsigned short hlds[2][16 * HD];  // 8 KB
  int tid = threadIdx.x;
  int lane = tid & 63;
  int w = tid >> 6;
  int p = blockIdx.x >> 5;
  int r0 = (blockIdx.x & 31) * 16;
  int cN = lane & 15;
  int quad = lane >> 4;
  int d = w * 16 + cN;

  {
    int* hz = (int*)hlds;
    for (int i = tid; i < 2 * 16 * HD / 2; i += 512) hz[i] = 0;
  }

  short8 Br[4], Bz[4], Bn[4];
#pragma unroll
  for (int kk = 0; kk < 4; ++kk) {
    int kbase = quad * 8 + kk * 32;
    const float* wr_ = Whh + (size_t)d * HD + kbase;
    const float* wz_ = Whh + (size_t)(128 + d) * HD + kbase;
    const float* wn_ = Whh + (size_t)(256 + d) * HD + kbase;
    float4 r0v = *(const float4*)wr_, r1v = *(const float4*)(wr_ + 4);
    float4 z0v = *(const float4*)wz_, z1v = *(const float4*)(wz_ + 4);
    float4 n0v = *(const float4*)wn_, n1v = *(const float4*)(wn_ + 4);
    short8 br, bz, bn;
    br[0]=(short)f2bf(r0v.x); br[1]=(short)f2bf(r0v.y); br[2]=(short)f2bf(r0v.z); br[3]=(short)f2bf(r0v.w);
    br[4]=(short)f2bf(r1v.x); br[5]=(short)f2bf(r1v.y); br[6]=(short)f2bf(r1v.z); br[7]=(short)f2bf(r1v.w);
    bz[0]=(short)f2bf(z0v.x); bz[1]=(short)f2bf(z0v.y); bz[2]=(short)f2bf(z0v.z); bz[3]=(short)f2bf(z0v.w);
    bz[4]=(short)f2bf(z1v.x); bz[5]=(short)f2bf(z1v.y); bz[6]=(short)f2bf(z1v.z); bz[7]=(short)f2bf(z1v.w);
    bn[0]=(short)f2bf(n0v.x); bn[1]=(short)f2bf(n0v.y); bn[2]=(short)f2bf(n0v.z); bn[3]=(short)f2bf(n0v.w);
    bn[4]=(short)f2bf(n1v.x); bn[5]=(short)f2bf(n1v.y); bn[6]=(short)f2bf(n1v.z); bn[7]=(short)f2bf(n1v.w);
    Br[kk] = br; Bz[kk] = bz; Bn[kk] = bn;
  }
  float cr = bhh[d] + bih[d];
  float cz = bhh[128 + d] + bih[128 + d];
  float bhn = bhh[256 + d], bin = bih[256 + d];

  int lens4[4];
  float hold[4];
  const float* gptr[4];
#pragma unroll
  for (int gq = 0; gq < 4; ++gq) {
    int lr = quad * 4 + gq;
    lens4[gq] = lengths[r0 + lr] - 1;
    hold[gq] = 0.f;
    gptr[gq] = gi_all + ((size_t)p * 25600 + (size_t)(r0 + lr) * LSEQ) * G3 + d;
  }

  int aoff[4];
#pragma unroll
  for (int kk = 0; kk < 4; ++kk)
    aoff[kk] = cN * 256 + (((quad * 8 + kk * 32) * 2) ^ ((cN & 7) << 4));
  int woff[4];
#pragma unroll
  for (int gq = 0; gq < 4; ++gq) {
    int lr = quad * 4 + gq;
    woff[gq] = lr * 256 + ((2 * d) ^ ((lr & 7) << 4));
  }

  float giaR[4], giaZ[4], giaN[4];
#pragma unroll
  for (int gq = 0; gq < 4; ++gq) {
    giaR[gq] = gptr[gq][0];
    giaZ[gq] = gptr[gq][HD];
    giaN[gq] = gptr[gq][2 * HD];
  }
  __syncthreads();

  for (int t = 0; t < LSEQ; ++t) {
    float gbR[4], gbZ[4], gbN[4];
#pragma unroll
    for (int gq = 0; gq < 4; ++gq) {
      const float* gp = gptr[gq] + (size_t)(t + 1) * G3;
      gbR[gq] = gp[0]; gbZ[gq] = gp[HD]; gbN[gq] = gp[2 * HD];
    }
    const char* hb = (const char*)hlds[t & 1];
    f32x4 accR = {0.f, 0.f, 0.f, 0.f};
    f32x4 accZ = {0.f, 0.f, 0.f, 0.f};
    f32x4 accN = {0.f, 0.f, 0.f, 0.f};
#pragma unroll
    for (int kk = 0; kk < 4; ++kk) {
      short8 A = *(const short8*)(hb + aoff[kk]);
      accR = __builtin_amdgcn_mfma_f32_16x16x32_bf16(A, Br[kk], accR, 0, 0, 0);
      accZ = __builtin_amdgcn_mfma_f32_16x16x32_bf16(A, Bz[kk], accZ, 0, 0, 0);
      accN = __builtin_amdgcn_mfma_f32_16x16x32_bf16(A, Bn[kk], accN, 0, 0, 0);
    }
    char* hw = (char*)hlds[(t + 1) & 1];
#pragma unroll
    for (int gq = 0; gq < 4; ++gq) {
      float rg = fast_sigm(giaR[gq] + accR[gq] + cr);
      float zg = fast_sigm(giaZ[gq] + accZ[gq] + cz);
      float ng = fast_tanh(giaN[gq] + bin + rg * (accN[gq] + bhn));
      float hnew = (1.f - zg) * ng + zg * hold[gq];
      hold[gq] = hnew;
      *(unsigned short*)(hw + woff[gq]) = f2bf(hnew);
      if (t == lens4[gq])
        ht_raw[((size_t)p * BSZ + r0 + quad * 4 + gq) * HD + d] = hnew;
    }
    __syncthreads();
#pragma unroll
    for (int gq = 0; gq < 4; ++gq) {
      giaR[gq] = gbR[gq]; giaZ[gq] = gbZ[gq]; giaN[gq] = gbN[gq];
    }
  }
}

// ---------------- layernorm ht + bf16 copy ---------------------------------
__global__ void ln_ht_kernel(float* __restrict__ ht,
                             const float* __restrict__ g2, const float* __restrict__ b2,
                             const float* __restrict__ g4, const float* __restrict__ b4,
                             unsigned short* __restrict__ hbf) {
  int w = threadIdx.x >> 6, l = threadIdx.x & 63;
  int r = blockIdx.x * 4 + w;
  if (r >= 2 * BSZ) return;
  const float* g = (r < BSZ) ? g2 : g4;
  const float* bb = (r < BSZ) ? b2 : b4;
  float a = ht[(size_t)r * HD + l];
  float b = ht[(size_t)r * HD + l + 64];
  float mu = wsum(a + b) * (1.f / HD);
  float v  = wsum(a * a + b * b) * (1.f / HD) - mu * mu;
  float rs = rsqrtf(v + 1e-5f);
  float va = (a - mu) * rs * g[l] + bb[l];
  float vb = (b - mu) * rs * g[l + 64] + bb[l + 64];
  hbf[(size_t)r * HD + l]      = f2bf(va);
  hbf[(size_t)r * HD + l + 64] = f2bf(vb);
}

// ---------------- scores: 32x32x16 MFMA + LDS-staged contiguous stores -----
#define JW 256
__global__ __launch_bounds__(512) void scores2_kernel(
    const unsigned short* __restrict__ hbf,
    const unsigned short* __restrict__ tbf,
    const unsigned short* __restrict__ cbf,
    const float* __restrict__ a1p, const float* __restrict__ a2p,
    float* __restrict__ out) {
  __shared__ float s1l[32 * JW];
  __shared__ float s2l[32 * JW];
  int tid = threadIdx.x;
  int w = tid >> 6, lane = tid & 63;
  int strip = blockIdx.x >> 4;
  int r0b = (blockIdx.x & 15) * 32;
  int j0 = strip * JW;
  int jc = j0 + w * 32 + (lane & 31);
  int jl = (jc < N_IT) ? jc : (N_IT - 1);
  int koA = (lane >> 5) * 8;

  f32x16 acc1 = {0.f}, acc2 = {0.f};
  const unsigned short* h1p = hbf + (size_t)(r0b + (lane & 31)) * HD + koA;
  const unsigned short* h2p = h1p + (size_t)BSZ * HD;
  const unsigned short* b1p = tbf + (size_t)(jl + 1) * HD + koA;
  const unsigned short* b2p = cbf + (size_t)(jl + 1) * HD + koA;
#pragma unroll
  for (int kk = 0; kk < 8; ++kk) {
    short8 A1 = *(const short8*)(h1p + kk * 16);
    short8 A2 = *(const short8*)(h2p + kk * 16);
    short8 B1 = *(const short8*)(b1p + kk * 16);
    short8 B2 = *(const short8*)(b2p + kk * 16);
    acc1 = __builtin_amdgcn_mfma_f32_32x32x16_bf16(A1, B1, acc1, 0, 0, 0);
    acc2 = __builtin_amdgcn_mfma_f32_32x32x16_bf16(A2, B2, acc2, 0, 0, 0);
  }
  int colb = w * 32 + (lane & 31);
#pragma unroll
  for (int q = 0; q < 16; ++q) {
    int row = (q & 3) + 8 * (q >> 2) + 4 * (lane >> 5);
    s1l[row * JW + colb] = acc1[q];
    s2l[row * JW + colb] = acc2[q];
  }
  __syncthreads();

  float sa1 = sigmf(a1p[0]);
  float sa2 = sigmf(a2p[0]);
  const size_t S = (size_t)BSZ * N_IT;
#pragma unroll
  for (int pss = 0; pss < 16; ++pss) {
    int idx = pss * 512 + tid;
    int row = idx >> 8;
    int jlc = idx & 255;
    int jg = j0 + jlc;
    if (jg < N_IT) {
      float s1 = s1l[idx];
      float s2 = s2l[idx];
      size_t o = (size_t)(r0b + row) * N_IT + jg;
      out[o]         = sa1 * s1 + sa2 * s2;
      out[S + o]     = s1;
      out[2 * S + o] = s2;
    }
  }
}

extern "C" void kernel_launch(void* const* d_in, const int* in_sizes, int n_in,
                              void* d_out, int out_size, void* d_ws, size_t ws_size,
                              hipStream_t stream) {
  const float* item_emb = (const float*)d_in[0];
  const float* prob_emb = (const float*)d_in[1];
  const float* W_cls    = (const float*)d_in[2];
  const float* a1       = (const float*)d_in[3];
  const float* a2       = (const float*)d_in[4];
  const float* Wih      = (const float*)d_in[5];
  const float* Whh      = (const float*)d_in[6];
  const float* bih      = (const float*)d_in[7];
  const float* bhh      = (const float*)d_in[8];
  const float* ln1_g = (const float*)d_in[9];
  const float* ln1_b = (const float*)d_in[10];
  const float* ln2_g = (const float*)d_in[11];
  const float* ln2_b = (const float*)d_in[12];
  const float* ln3_g = (const float*)d_in[13];
  const float* ln3_b = (const float*)d_in[14];
  const float* ln4_g = (const float*)d_in[15];
  const float* ln4_b = (const float*)d_in[16];
  const int* inp_sess = (const int*)d_in[19];
  const int* lengths  = (const int*)d_in[20];
  const int* adj      = (const int*)d_in[21];
  float* out = (float*)d_out;

  float* ws = (float*)d_ws;
  const size_t SZ_ROW = (size_t)N_IT * HD;
  float* xn  = ws;
  float* o1  = xn + SZ_ROW;
  float* o2  = o1 + SZ_ROW;
  float* gi  = o2 + SZ_ROW + 2 * (size_t)NI * HD;
  float* htb = gi + (size_t)2 * 25600 * G3;

  // aliases into dead regions:
  unsigned* xnb = (unsigned*)gi;                    // dead before gi2 writes gi
  unsigned short* tbf = (unsigned short*)xn;        // written by iv (xn dead after hop2)
  unsigned short* cbf = (unsigned short*)o2;        // written by cls (o2 dead after iv)
  unsigned short* hbf = (unsigned short*)o1;        // written by ln_ht (o1 dead after iv)
  unsigned short* wbf = (unsigned short*)(o2 + 3400000);  // past cbf

  int nb4 = (N_IT + 3) / 4;
  int nb4i = (NI + 3) / 4;

  norm_kernel<<<nb4, 256, 0, stream>>>(item_emb + HD, xn, xnb, N_IT);
  routing_kernel<<<nb4, 256, 0, stream>>>(xn, xnb, adj + MNB, o1);
  norm_kernel<<<nb4, 256, 0, stream>>>(o1, xn, xnb, N_IT);
  routing_kernel<<<nb4, 256, 0, stream>>>(xn, xnb, adj + MNB, o2);
  iv_kernel<<<nb4i, 256, 0, stream>>>(item_emb, o1, o2, ln1_g, ln1_b, tbf);
  cls_kernel<<<nb4i, 256, 0, stream>>>(prob_emb, W_cls, ln3_g, ln3_b, cbf);
  wbf_kernel<<<192, 256, 0, stream>>>(Wih, wbf);
  gi2_kernel<<<3200, 256, 0, stream>>>(tbf, cbf, inp_sess, wbf, gi);
  gru_mfma_kernel<<<64, 512, 0, stream>>>(gi, Whh, bih, bhh, lengths, htb);
  ln_ht_kernel<<<256, 256, 0, stream>>>(htb, ln2_g, ln2_b, ln4_g, ln4_b, hbf);
  scores2_kernel<<<196 * 16, 512, 0, stream>>>(hbf, tbf, cbf, a1, a2, out);
}